// Round 11
// baseline (250.581 us; speedup 1.0000x reference)
//
#include <hip/hip_runtime.h>
#include <math.h>

#define BATCH 16384
#define INFEAT 256
#define HID 128
#define NQ 10
#define NL 4
#define GSTRIDE 48   // floats per gate in gtab

typedef float v2f __attribute__((ext_vector_type(2)));

// ---------- cross-lane xor helper: DPP for 1,2,3,8; ds_swizzle for <32; shfl for 32+ ----------
template<int M>
__device__ __forceinline__ float lxor(float x) {
    if constexpr (M == 0) {
        return x;
    } else if constexpr (M < 4) {
        constexpr int ctrl = (0 ^ M) | ((1 ^ M) << 2) | ((2 ^ M) << 4) | ((3 ^ M) << 6);
        return __int_as_float(__builtin_amdgcn_update_dpp(
            __float_as_int(x), __float_as_int(x), ctrl, 0xF, 0xF, false));
    } else if constexpr (M == 8) {
        return __int_as_float(__builtin_amdgcn_update_dpp(
            __float_as_int(x), __float_as_int(x), 0x128, 0xF, 0xF, false));  // ROW_ROR:8
    } else if constexpr (M < 32) {
        return __int_as_float(__builtin_amdgcn_ds_swizzle(
            __float_as_int(x), (M << 10) | 0x1F));
    } else {
        return __shfl_xor(x, M, 64);
    }
}

// full 64-lane sum — proven lxor ladder (permlane-swap on same-SSA copies miscompiles; r5)
__device__ __forceinline__ float wave_sum(float v) {
    v += lxor<1>(v); v += lxor<2>(v); v += lxor<8>(v);
    v += lxor<4>(v); v += lxor<16>(v); v += lxor<32>(v);
    return v;
}

// gfx950 VALU cross-lane exchange; a and b MUST be distinct SSA values.
template<int HALF>
__device__ __forceinline__ void swap_pl(float& a, float& b) {
    if constexpr (HALF == 32)
        asm("v_permlane32_swap_b32 %0, %1" : "+v"(a), "+v"(b));
    else
        asm("v_permlane16_swap_b32 %0, %1" : "+v"(a), "+v"(b));
}

// ---------- explicit VOP3P packed-f32 helpers ----------
__device__ __forceinline__ v2f pks_mul(v2f c, v2f a) {
    v2f d; asm("v_pk_mul_f32 %0, %1, %2" : "=v"(d) : "s"(c), "v"(a)); return d;
}
__device__ __forceinline__ v2f pks_fma(v2f c, v2f a, v2f b) {
    v2f d; asm("v_pk_fma_f32 %0, %1, %2, %3" : "=v"(d) : "s"(c), "v"(a), "v"(b)); return d;
}
__device__ __forceinline__ v2f pkv_mul(v2f c, v2f a) {
    v2f d; asm("v_pk_mul_f32 %0, %1, %2" : "=v"(d) : "v"(c), "v"(a)); return d;
}
__device__ __forceinline__ v2f pkv_fma(v2f c, v2f a, v2f b) {
    v2f d; asm("v_pk_fma_f32 %0, %1, %2, %3" : "=v"(d) : "v"(c), "v"(a), "v"(b)); return d;
}
// q3 variants: src1 broadcast from its LOW or HIGH 32-bit half via op_sel
__device__ __forceinline__ v2f pks_mul_blo(v2f c, v2f a) {
    v2f d; asm("v_pk_mul_f32 %0, %1, %2 op_sel:[0,0] op_sel_hi:[1,0]"
               : "=v"(d) : "s"(c), "v"(a)); return d;
}
__device__ __forceinline__ v2f pks_fma_blo(v2f c, v2f a, v2f b) {
    v2f d; asm("v_pk_fma_f32 %0, %1, %2, %3 op_sel:[0,0,0] op_sel_hi:[1,0,1]"
               : "=v"(d) : "s"(c), "v"(a), "v"(b)); return d;
}
__device__ __forceinline__ v2f pks_fma_bhi(v2f c, v2f a, v2f b) {
    v2f d; asm("v_pk_fma_f32 %0, %1, %2, %3 op_sel:[0,1,0] op_sel_hi:[1,1,1]"
               : "=v"(d) : "s"(c), "v"(a), "v"(b)); return d;
}

// ---- state: v2f AR[8], AI[8]; element e = 2k+h; qubit w(0..3) <-> e-bit(3-w);
// ---- qubits 4..9 <-> lane bits 5..0.
__device__ __forceinline__ float getv(const v2f (&A)[8], int e) {
    return (e & 1) ? A[e >> 1].y : A[e >> 1].x;
}
__device__ __forceinline__ void setv(v2f (&A)[8], int e, float v) {
    if (e & 1) A[e >> 1].y = v; else A[e >> 1].x = v;
}

// gate table layout (48 floats):
// [0..7]  scalars m00r,m00i,m01r,m01i,m10r,m10i,m11r,m11i
// [8..11] negated scalars -m00i,-m01i,-m10i,-m11i
// [12..35] splat pairs c00r,c00i,c00in,c01r,c01i,c01in,c10r,c10i,c10in,c11r,c11i,c11in
// [36..47] q3 pairs P0,P1,P1n,P2,P3,P3n

template<int KM>
__device__ __forceinline__ void reg_gate_asm(const float* __restrict__ g,
                                             v2f (&AR)[8], v2f (&AI)[8]) {
    const v2f* __restrict__ gp = (const v2f*)g;
    const v2f c00r = gp[6],  c00i = gp[7],  c00in = gp[8];
    const v2f c01r = gp[9],  c01i = gp[10], c01in = gp[11];
    const v2f c10r = gp[12], c10i = gp[13], c10in = gp[14];
    const v2f c11r = gp[15], c11i = gp[16], c11in = gp[17];
#pragma unroll
    for (int k0 = 0; k0 < 8; ++k0) {
        if (k0 & KM) continue;
        const int k1 = k0 | KM;
        v2f A0 = AR[k0], I0 = AI[k0], A1 = AR[k1], I1 = AI[k1];
        v2f t = pks_mul(c00r, A0); t = pks_fma(c00in, I0, t);
        t = pks_fma(c01r, A1, t);  AR[k0] = pks_fma(c01in, I1, t);
        v2f u = pks_mul(c00r, I0); u = pks_fma(c00i, A0, u);
        u = pks_fma(c01r, I1, u);  AI[k0] = pks_fma(c01i, A1, u);
        v2f t2 = pks_mul(c10r, A0); t2 = pks_fma(c10in, I0, t2);
        t2 = pks_fma(c11r, A1, t2); AR[k1] = pks_fma(c11in, I1, t2);
        v2f u2 = pks_mul(c10r, I0); u2 = pks_fma(c10i, A0, u2);
        u2 = pks_fma(c11r, I1, u2); AI[k1] = pks_fma(c11i, A1, u2);
    }
}

__device__ __forceinline__ void reg_gate_q3_asm(const float* __restrict__ g,
                                                v2f (&AR)[8], v2f (&AI)[8]) {
    const v2f* __restrict__ gp = (const v2f*)g;
    const v2f P0 = gp[18], P1 = gp[19], P1n = gp[20];
    const v2f P2 = gp[21], P3 = gp[22], P3n = gp[23];
#pragma unroll
    for (int k = 0; k < 8; ++k) {
        v2f t = pks_mul_blo(P0, AR[k]);
        t = pks_fma_blo(P1n, AI[k], t);
        t = pks_fma_bhi(P2, AR[k], t);
        v2f nR = pks_fma_bhi(P3n, AI[k], t);
        v2f u = pks_mul_blo(P0, AI[k]);
        u = pks_fma_blo(P1, AR[k], u);
        u = pks_fma_bhi(P2, AI[k], u);
        v2f nI = pks_fma_bhi(P3, AR[k], u);
        AR[k] = nR; AI[k] = nI;
    }
}

template<int LB>
__device__ __forceinline__ void lane_gate_asm(const float* __restrict__ g, int lane,
                                              v2f (&AR)[8], v2f (&AI)[8]) {
    const bool side = (lane >> LB) & 1;
    const float cmr = side ? g[6] : g[0];
    const float cmi = side ? g[7] : g[1];
    const float cmin = side ? g[11] : g[8];
    const float cpr = side ? g[4] : g[2];
    const float cpi = side ? g[5] : g[3];
    const float cpin = side ? g[10] : g[9];
    v2f Cmr; Cmr.x = cmr; Cmr.y = cmr;
    v2f Cmi; Cmi.x = cmi; Cmi.y = cmi;
    v2f Cmin; Cmin.x = cmin; Cmin.y = cmin;
    v2f Cpr; Cpr.x = cpr; Cpr.y = cpr;
    v2f Cpi; Cpi.x = cpi; Cpi.y = cpi;
    v2f Cpin; Cpin.x = cpin; Cpin.y = cpin;
#pragma unroll
    for (int k = 0; k < 8; ++k) {
        v2f PR, PI;
        PR.x = lxor<(1 << LB)>(AR[k].x); PR.y = lxor<(1 << LB)>(AR[k].y);
        PI.x = lxor<(1 << LB)>(AI[k].x); PI.y = lxor<(1 << LB)>(AI[k].y);
        v2f t = pkv_mul(Cmr, AR[k]); t = pkv_fma(Cmin, AI[k], t);
        t = pkv_fma(Cpr, PR, t);     v2f NR = pkv_fma(Cpin, PI, t);
        v2f u = pkv_mul(Cmr, AI[k]); u = pkv_fma(Cmi, AR[k], u);
        u = pkv_fma(Cpr, PI, u);     v2f NI = pkv_fma(Cpi, PR, u);
        AR[k] = NR; AI[k] = NI;
    }
}

template<int HALF>
__device__ __forceinline__ void lane_gate_pl_asm(const float* __restrict__ g,
                                                 v2f (&AR)[8], v2f (&AI)[8]) {
    const v2f* __restrict__ gp = (const v2f*)g;
    const v2f c00r = gp[6],  c00i = gp[7],  c00in = gp[8];
    const v2f c01r = gp[9],  c01i = gp[10], c01in = gp[11];
    const v2f c10r = gp[12], c10i = gp[13], c10in = gp[14];
    const v2f c11r = gp[15], c11i = gp[16], c11in = gp[17];
#pragma unroll
    for (int k0 = 0; k0 < 8; k0 += 2) {
        const int k1 = k0 + 1;
        float Xr0 = AR[k0].x, Xr1 = AR[k0].y, Yr0 = AR[k1].x, Yr1 = AR[k1].y;
        float Xi0 = AI[k0].x, Xi1 = AI[k0].y, Yi0 = AI[k1].x, Yi1 = AI[k1].y;
        swap_pl<HALF>(Xr0, Yr0); swap_pl<HALF>(Xr1, Yr1);
        swap_pl<HALF>(Xi0, Yi0); swap_pl<HALF>(Xi1, Yi1);
        v2f Xr; Xr.x = Xr0; Xr.y = Xr1;  v2f Yr; Yr.x = Yr0; Yr.y = Yr1;
        v2f Xi; Xi.x = Xi0; Xi.y = Xi1;  v2f Yi; Yi.x = Yi0; Yi.y = Yi1;
        v2f t = pks_mul(c00r, Xr); t = pks_fma(c00in, Xi, t);
        t = pks_fma(c01r, Yr, t);  v2f Pr = pks_fma(c01in, Yi, t);
        v2f u = pks_mul(c00r, Xi); u = pks_fma(c00i, Xr, u);
        u = pks_fma(c01r, Yi, u);  v2f Pi = pks_fma(c01i, Yr, u);
        v2f t2 = pks_mul(c10r, Xr); t2 = pks_fma(c10in, Xi, t2);
        t2 = pks_fma(c11r, Yr, t2); v2f Qr = pks_fma(c11in, Yi, t2);
        v2f u2 = pks_mul(c10r, Xi); u2 = pks_fma(c10i, Xr, u2);
        u2 = pks_fma(c11r, Yi, u2); v2f Qi = pks_fma(c11i, Yr, u2);
        float pr0 = Pr.x, pr1 = Pr.y, qr0 = Qr.x, qr1 = Qr.y;
        float pi0 = Pi.x, pi1 = Pi.y, qi0 = Qi.x, qi1 = Qi.y;
        swap_pl<HALF>(pr0, qr0); swap_pl<HALF>(pr1, qr1);
        swap_pl<HALF>(pi0, qi0); swap_pl<HALF>(pi1, qi1);
        AR[k0].x = pr0; AR[k0].y = pr1; AR[k1].x = qr0; AR[k1].y = qr1;
        AI[k0].x = pi0; AI[k0].y = pi1; AI[k1].x = qi0; AI[k1].y = qi1;
    }
}

// ---- compile-time CNOT-ring tables (element index e, 4 bits) ----
constexpr int rr_src(int rs, int e) {
    int s = e;
    for (int i = 3 - rs; i >= 0; --i) s ^= ((s >> (3 - i)) & 1) << (3 - i - rs);
    return s;
}
constexpr int rl_mask(int rs, int e) {
    int m = 0;
    for (int i = (4 - rs < 0 ? 0 : 4 - rs); i <= 3; ++i)
        if ((e >> (3 - i)) & 1) m |= 1 << (9 - i - rs);
    return m;
}

template<int L>
__device__ __forceinline__ void do_layer(const float* __restrict__ gt, int lane,
                                         v2f (&AR)[8], v2f (&AI)[8]) {
    constexpr int rs = L + 1;
    const float* __restrict__ gb = gt + L * NQ * GSTRIDE;
    reg_gate_asm<4>(gb + 0 * GSTRIDE, AR, AI);   // qubit0: e-mask 8
    reg_gate_asm<2>(gb + 1 * GSTRIDE, AR, AI);   // qubit1: e-mask 4
    reg_gate_asm<1>(gb + 2 * GSTRIDE, AR, AI);   // qubit2: e-mask 2
    reg_gate_q3_asm(gb + 3 * GSTRIDE, AR, AI);   // qubit3: e-mask 1
    lane_gate_pl_asm<32>(gb + 4 * GSTRIDE, AR, AI);
    lane_gate_pl_asm<16>(gb + 5 * GSTRIDE, AR, AI);
    lane_gate_asm<3>(gb + 6 * GSTRIDE, lane, AR, AI);
    lane_gate_asm<2>(gb + 7 * GSTRIDE, lane, AR, AI);
    lane_gate_asm<1>(gb + 8 * GSTRIDE, lane, AR, AI);
    lane_gate_asm<0>(gb + 9 * GSTRIDE, lane, AR, AI);
    // ---- CNOT ring: RR+RL+LL folded into one per-element bpermute gather ----
    int y = lane;
#pragma unroll
    for (int i = 9 - rs; i >= 4; --i)
        y ^= ((y >> (9 - i)) & 1) << (9 - i - rs);
    const int base = y << 2;
    {
        float nr[16], ni[16];
#pragma unroll
        for (int e = 0; e < 16; ++e) {
            const int src = rr_src(rs, e);
            const int am  = rl_mask(rs, e) << 2;
            nr[e] = __int_as_float(__builtin_amdgcn_ds_bpermute(base ^ am, __float_as_int(getv(AR, src))));
            ni[e] = __int_as_float(__builtin_amdgcn_ds_bpermute(base ^ am, __float_as_int(getv(AI, src))));
        }
#pragma unroll
        for (int k = 0; k < 8; ++k) {
            AR[k].x = nr[2 * k]; AR[k].y = nr[2 * k + 1];
            AI[k].x = ni[2 * k]; AI[k].y = ni[2 * k + 1];
        }
    }
    // LR: predicated element-pair swaps
#pragma unroll
    for (int i = 10 - rs; i <= 9; ++i) {
        const bool p = (lane >> (9 - i)) & 1;
        const int tm = 1 << (13 - i - rs);
#pragma unroll
        for (int e = 0; e < 16; ++e) {
            if (!(e & tm)) {
                const int e1 = e | tm;
                float v0r = getv(AR, e), v1r = getv(AR, e1);
                setv(AR, e, p ? v1r : v0r); setv(AR, e1, p ? v0r : v1r);
                float v0i = getv(AI, e), v1i = getv(AI, e1);
                setv(AI, e, p ? v1i : v0i); setv(AI, e1, p ? v0i : v1i);
            }
        }
    }
}

__device__ __forceinline__ float ftanh(float s) {
    float e = __expf(2.f * s);
    return 1.f - 2.f / (e + 1.f);
}

// ---------------- prep: gate table ONLY (1 block). The 128-block W1-transpose
// prep cost ~40 us of wall time (r4-r10: total-fused gap 42-47 us vs 3-6 us in
// r2/r3 without it); fused now reads W1 directly (L2-resident, 128 KB).
__global__ void prep_kernel(const float* __restrict__ qw, float* __restrict__ gtab) {
    int t = threadIdx.x;
    if (t < NL * NQ) {
        float phi = qw[t * 3 + 0], th = qw[t * 3 + 1], om = qw[t * 3 + 2];
        float c = __cosf(th * 0.5f), s = __sinf(th * 0.5f);
        float a = 0.5f * (phi + om), b = 0.5f * (phi - om);
        float ca = __cosf(a), sa = __sinf(a);
        float cb = __cosf(b), sb = __sinf(b);
        float m00r = ca * c,  m00i = -sa * c;
        float m01r = -cb * s, m01i = -sb * s;
        float m10r = cb * s,  m10i = -sb * s;
        float m11r = ca * c,  m11i = sa * c;
        float* g = gtab + t * GSTRIDE;
        g[0] = m00r; g[1] = m00i; g[2] = m01r; g[3] = m01i;
        g[4] = m10r; g[5] = m10i; g[6] = m11r; g[7] = m11i;
        g[8] = -m00i; g[9] = -m01i; g[10] = -m10i; g[11] = -m11i;
        g[12] = g[13] = m00r;  g[14] = g[15] = m00i;  g[16] = g[17] = -m00i;
        g[18] = g[19] = m01r;  g[20] = g[21] = m01i;  g[22] = g[23] = -m01i;
        g[24] = g[25] = m10r;  g[26] = g[27] = m10i;  g[28] = g[29] = -m10i;
        g[30] = g[31] = m11r;  g[32] = g[33] = m11i;  g[34] = g[35] = -m11i;
        g[36] = m00r;  g[37] = m10r;
        g[38] = m00i;  g[39] = m10i;
        g[40] = -m00i; g[41] = -m10i;
        g[42] = m01r;  g[43] = m11r;
        g[44] = m01i;  g[45] = m11i;
        g[46] = -m01i; g[47] = -m11i;
    }
}

// ---------------- fused kernel: K-split MLP (direct W1 reads) -> circuit -> head ----------------
// NO launch_bounds minimum: (256,6)->40 VGPR/660MB spill (r8), (256,4)->64 VGPR/
// 270MB spill (r9). Plain (256) allocates ~84 VGPR spill-free (r7/r10).
__global__ __launch_bounds__(256) void fused_kernel(
    const float* __restrict__ x, const float* __restrict__ W1,
    const float* __restrict__ b1, const float* __restrict__ W2,
    const float* __restrict__ b2, const float* __restrict__ gtab,
    const float* __restrict__ W3, const float* __restrict__ b3,
    const float* __restrict__ W4, const float* __restrict__ b4,
    float* __restrict__ out)
{
    __shared__ float w3s[HID * 11];
    __shared__ float b3s[HID], w4s[HID];
    __shared__ float b4s;
    __shared__ v2f hpart[4][4][64];   // [k-slice wave][row][lane(2 cols)]

    const int t = threadIdx.x;
    for (int f = t; f < HID * NQ; f += 256) {
        int c = f / NQ, k = f - c * NQ;
        w3s[c * 11 + k] = W3[f];
    }
    if (t < HID) { b3s[t] = b3[t]; w4s[t] = W4[t]; }
    if (t == 0) b4s = b4[0];

    const int lane = t & 63;
    const int wid = t >> 6;
    const int row0 = blockIdx.x * 4;
    const int ukw = __builtin_amdgcn_readfirstlane(wid);

    // ---- MLP phase 1: partial h for all 4 rows over k-slice [64*ukw, 64*ukw+64) ----
    // x rows via wave-uniform loads (scalar path); W1 rows 2*lane, 2*lane+1 read
    // directly (row-major; uncoalesced across lanes but 128 KB -> L2-resident).
    v2f acc[4];
#pragma unroll
    for (int r = 0; r < 4; ++r) acc[r] = (v2f)(0.f);
    const float4* __restrict__ xr0 = (const float4*)(x + (size_t)(row0 + 0) * INFEAT + ukw * 64);
    const float4* __restrict__ xr1 = (const float4*)(x + (size_t)(row0 + 1) * INFEAT + ukw * 64);
    const float4* __restrict__ xr2 = (const float4*)(x + (size_t)(row0 + 2) * INFEAT + ukw * 64);
    const float4* __restrict__ xr3 = (const float4*)(x + (size_t)(row0 + 3) * INFEAT + ukw * 64);
    const float4* __restrict__ wr0 = (const float4*)(W1 + (size_t)(2 * lane) * INFEAT + ukw * 64);
    const float4* __restrict__ wr1 = (const float4*)(W1 + (size_t)(2 * lane + 1) * INFEAT + ukw * 64);
#pragma unroll 4
    for (int kk4 = 0; kk4 < 16; ++kk4) {
        float4 wa = wr0[kk4];
        float4 wb = wr1[kk4];
        float4 x0 = xr0[kk4], x1 = xr1[kk4], x2 = xr2[kk4], x3 = xr3[kk4];
        float xk[4][4] = {{x0.x, x0.y, x0.z, x0.w}, {x1.x, x1.y, x1.z, x1.w},
                          {x2.x, x2.y, x2.z, x2.w}, {x3.x, x3.y, x3.z, x3.w}};
        float wav[4] = {wa.x, wa.y, wa.z, wa.w};
        float wbv[4] = {wb.x, wb.y, wb.z, wb.w};
#pragma unroll
        for (int r = 0; r < 4; ++r) {
#pragma unroll
            for (int j = 0; j < 4; ++j) {
                acc[r].x = fmaf(xk[r][j], wav[j], acc[r].x);
                acc[r].y = fmaf(xk[r][j], wbv[j], acc[r].y);
            }
        }
    }
#pragma unroll
    for (int r = 0; r < 4; ++r) hpart[wid][r][lane] = acc[r];
    __syncthreads();

    // ---- MLP phase 2 ----
    v2f hs = hpart[0][wid][lane];
    hs += hpart[1][wid][lane];
    hs += hpart[2][wid][lane];
    hs += hpart[3][wid][lane];
    float2 b1v = ((const float2*)b1)[lane];
    float h0 = fmaxf(hs.x + b1v.x, 0.f);
    float h1 = fmaxf(hs.y + b1v.y, 0.f);

    const int row = row0 + wid;

    // ---- angles = tanh(h@W2^T + b2) ----
    float cth[NQ], sth[NQ];
#pragma unroll
    for (int w = 0; w < NQ; ++w) {
        float2 w2v = ((const float2*)(W2 + (size_t)w * HID))[lane];
        float aw = wave_sum(fmaf(h0, w2v.x, h1 * w2v.y)) + b2[w];
        float th = ftanh(aw) * 0.5f;
        cth[w] = __cosf(th); sth[w] = __sinf(th);
    }

    // ---- RY product state ----
    float fl = 1.f;
#pragma unroll
    for (int w = 4; w < 10; ++w)
        fl *= ((lane >> (9 - w)) & 1) ? sth[w] : cth[w];
    v2f AR[8], AI[8];
    {
        float ev[16];
#pragma unroll
        for (int e = 0; e < 16; ++e) {
            float g = fl;
#pragma unroll
            for (int w = 0; w < 4; ++w)
                g *= ((e >> (3 - w)) & 1) ? sth[w] : cth[w];
            ev[e] = g;
        }
#pragma unroll
        for (int k = 0; k < 8; ++k) {
            AR[k].x = ev[2 * k]; AR[k].y = ev[2 * k + 1];
            AI[k] = (v2f)(0.f);
        }
    }

    // ---- 4 layers ----
    do_layer<0>(gtab, lane, AR, AI);
    do_layer<1>(gtab, lane, AR, AI);
    do_layer<2>(gtab, lane, AR, AI);
    do_layer<3>(gtab, lane, AR, AI);

    // ---- Z expectations ----
    v2f Pk[8];
#pragma unroll
    for (int k = 0; k < 8; ++k) Pk[k] = AR[k] * AR[k] + AI[k] * AI[k];
    v2f S = Pk[0] + Pk[1] + Pk[2] + Pk[3] + Pk[4] + Pk[5] + Pk[6] + Pk[7];
    float ptot = S.x + S.y;
    v2f Sq0 = Pk[4] + Pk[5] + Pk[6] + Pk[7];
    v2f Sq1 = Pk[2] + Pk[3] + Pk[6] + Pk[7];
    v2f Sq2 = Pk[1] + Pk[3] + Pk[5] + Pk[7];
    float es0 = wave_sum(ptot - 2.f * (Sq0.x + Sq0.y));
    float es1 = wave_sum(ptot - 2.f * (Sq1.x + Sq1.y));
    float es2 = wave_sum(ptot - 2.f * (Sq2.x + Sq2.y));
    float es3 = wave_sum(ptot - 2.f * S.y);
    // lane-qubit expectations via one Walsh-Hadamard butterfly on ptot
    float Wv = ptot;
    {
        float p;
        p = lxor<1>(Wv);  Wv = (lane & 1)  ? p - Wv : Wv + p;
        p = lxor<2>(Wv);  Wv = (lane & 2)  ? p - Wv : Wv + p;
        p = lxor<4>(Wv);  Wv = (lane & 4)  ? p - Wv : Wv + p;
        p = lxor<8>(Wv);  Wv = (lane & 8)  ? p - Wv : Wv + p;
        p = lxor<16>(Wv); Wv = (lane & 16) ? p - Wv : Wv + p;
        p = lxor<32>(Wv); Wv = (lane & 32) ? p - Wv : Wv + p;
    }
    const int wvi = __float_as_int(Wv);
    float es[NQ];
    es[0] = es0; es[1] = es1; es[2] = es2; es[3] = es3;
    es[4] = __int_as_float(__builtin_amdgcn_readlane(wvi, 32));
    es[5] = __int_as_float(__builtin_amdgcn_readlane(wvi, 16));
    es[6] = __int_as_float(__builtin_amdgcn_readlane(wvi, 8));
    es[7] = __int_as_float(__builtin_amdgcn_readlane(wvi, 4));
    es[8] = __int_as_float(__builtin_amdgcn_readlane(wvi, 2));
    es[9] = __int_as_float(__builtin_amdgcn_readlane(wvi, 1));

    // ---- head ----
    float accv = 0.f;
#pragma unroll
    for (int j = 0; j < 2; ++j) {
        int c = lane + 64 * j;
        float d = b3s[c];
#pragma unroll
        for (int k = 0; k < NQ; ++k) d = fmaf(w3s[c * 11 + k], es[k], d);
        d = fmaxf(d, 0.f);
        accv = fmaf(d, w4s[c], accv);
    }
    accv = wave_sum(accv);
    if (lane == 0) out[row] = accv + b4s;
}

extern "C" void kernel_launch(void* const* d_in, const int* in_sizes, int n_in,
                              void* d_out, int out_size, void* d_ws, size_t ws_size,
                              hipStream_t stream) {
    const float* x  = (const float*)d_in[0];
    const float* W1 = (const float*)d_in[1];
    const float* b1 = (const float*)d_in[2];
    const float* W2 = (const float*)d_in[3];
    const float* b2 = (const float*)d_in[4];
    const float* qw = (const float*)d_in[5];
    const float* W3 = (const float*)d_in[6];
    const float* b3 = (const float*)d_in[7];
    const float* W4 = (const float*)d_in[8];
    const float* b4 = (const float*)d_in[9];
    float* gtab = (float*)d_ws;                 // 40*48 = 1920 floats
    float* out  = (float*)d_out;

    prep_kernel<<<1, 64, 0, stream>>>(qw, gtab);
    fused_kernel<<<BATCH / 4, 256, 0, stream>>>(x, W1, b1, W2, b2, gtab, W3, b3, W4, b4, out);
}

// Round 12
// 224.464 us; speedup vs baseline: 1.1164x; 1.1164x over previous
//
#include <hip/hip_runtime.h>
#include <math.h>

#define BATCH 16384
#define INFEAT 256
#define HID 128
#define NQ 10
#define NL 4
#define GSTRIDE 48   // floats per gate in gtab

typedef float v2f __attribute__((ext_vector_type(2)));

// ---------- cross-lane xor helper: DPP for 1,2,3,8; ds_swizzle for <32; shfl for 32+ ----------
template<int M>
__device__ __forceinline__ float lxor(float x) {
    if constexpr (M == 0) {
        return x;
    } else if constexpr (M < 4) {
        constexpr int ctrl = (0 ^ M) | ((1 ^ M) << 2) | ((2 ^ M) << 4) | ((3 ^ M) << 6);
        return __int_as_float(__builtin_amdgcn_update_dpp(
            __float_as_int(x), __float_as_int(x), ctrl, 0xF, 0xF, false));
    } else if constexpr (M == 8) {
        return __int_as_float(__builtin_amdgcn_update_dpp(
            __float_as_int(x), __float_as_int(x), 0x128, 0xF, 0xF, false));  // ROW_ROR:8
    } else if constexpr (M < 32) {
        return __int_as_float(__builtin_amdgcn_ds_swizzle(
            __float_as_int(x), (M << 10) | 0x1F));
    } else {
        return __shfl_xor(x, M, 64);
    }
}

// full 64-lane sum — proven lxor ladder (permlane-swap on same-SSA copies miscompiles; r5)
__device__ __forceinline__ float wave_sum(float v) {
    v += lxor<1>(v); v += lxor<2>(v); v += lxor<8>(v);
    v += lxor<4>(v); v += lxor<16>(v); v += lxor<32>(v);
    return v;
}

// gfx950 VALU cross-lane exchange; a and b MUST be distinct SSA values.
template<int HALF>
__device__ __forceinline__ void swap_pl(float& a, float& b) {
    if constexpr (HALF == 32)
        asm("v_permlane32_swap_b32 %0, %1" : "+v"(a), "+v"(b));
    else
        asm("v_permlane16_swap_b32 %0, %1" : "+v"(a), "+v"(b));
}

// ---------- explicit VOP3P packed-f32 helpers ----------
__device__ __forceinline__ v2f pks_mul(v2f c, v2f a) {
    v2f d; asm("v_pk_mul_f32 %0, %1, %2" : "=v"(d) : "s"(c), "v"(a)); return d;
}
__device__ __forceinline__ v2f pks_fma(v2f c, v2f a, v2f b) {
    v2f d; asm("v_pk_fma_f32 %0, %1, %2, %3" : "=v"(d) : "s"(c), "v"(a), "v"(b)); return d;
}
__device__ __forceinline__ v2f pkv_mul(v2f c, v2f a) {
    v2f d; asm("v_pk_mul_f32 %0, %1, %2" : "=v"(d) : "v"(c), "v"(a)); return d;
}
__device__ __forceinline__ v2f pkv_fma(v2f c, v2f a, v2f b) {
    v2f d; asm("v_pk_fma_f32 %0, %1, %2, %3" : "=v"(d) : "v"(c), "v"(a), "v"(b)); return d;
}
// q3 variants: src1 broadcast from its LOW or HIGH 32-bit half via op_sel
__device__ __forceinline__ v2f pks_mul_blo(v2f c, v2f a) {
    v2f d; asm("v_pk_mul_f32 %0, %1, %2 op_sel:[0,0] op_sel_hi:[1,0]"
               : "=v"(d) : "s"(c), "v"(a)); return d;
}
__device__ __forceinline__ v2f pks_fma_blo(v2f c, v2f a, v2f b) {
    v2f d; asm("v_pk_fma_f32 %0, %1, %2, %3 op_sel:[0,0,0] op_sel_hi:[1,0,1]"
               : "=v"(d) : "s"(c), "v"(a), "v"(b)); return d;
}
__device__ __forceinline__ v2f pks_fma_bhi(v2f c, v2f a, v2f b) {
    v2f d; asm("v_pk_fma_f32 %0, %1, %2, %3 op_sel:[0,1,0] op_sel_hi:[1,1,1]"
               : "=v"(d) : "s"(c), "v"(a), "v"(b)); return d;
}

// ---- state: v2f AR[8], AI[8]; element e = 2k+h; qubit w(0..3) <-> e-bit(3-w);
// ---- qubits 4..9 <-> lane bits 5..0.
__device__ __forceinline__ float getv(const v2f (&A)[8], int e) {
    return (e & 1) ? A[e >> 1].y : A[e >> 1].x;
}
__device__ __forceinline__ void setv(v2f (&A)[8], int e, float v) {
    if (e & 1) A[e >> 1].y = v; else A[e >> 1].x = v;
}

// gate table layout (48 floats):
// [0..7]  scalars m00r,m00i,m01r,m01i,m10r,m10i,m11r,m11i
// [8..11] negated scalars -m00i,-m01i,-m10i,-m11i
// [12..35] splat pairs c00r,c00i,c00in,c01r,c01i,c01in,c10r,c10i,c10in,c11r,c11i,c11in
// [36..47] q3 pairs P0,P1,P1n,P2,P3,P3n

template<int KM>
__device__ __forceinline__ void reg_gate_asm(const float* __restrict__ g,
                                             v2f (&AR)[8], v2f (&AI)[8]) {
    const v2f* __restrict__ gp = (const v2f*)g;
    const v2f c00r = gp[6],  c00i = gp[7],  c00in = gp[8];
    const v2f c01r = gp[9],  c01i = gp[10], c01in = gp[11];
    const v2f c10r = gp[12], c10i = gp[13], c10in = gp[14];
    const v2f c11r = gp[15], c11i = gp[16], c11in = gp[17];
#pragma unroll
    for (int k0 = 0; k0 < 8; ++k0) {
        if (k0 & KM) continue;
        const int k1 = k0 | KM;
        v2f A0 = AR[k0], I0 = AI[k0], A1 = AR[k1], I1 = AI[k1];
        v2f t = pks_mul(c00r, A0); t = pks_fma(c00in, I0, t);
        t = pks_fma(c01r, A1, t);  AR[k0] = pks_fma(c01in, I1, t);
        v2f u = pks_mul(c00r, I0); u = pks_fma(c00i, A0, u);
        u = pks_fma(c01r, I1, u);  AI[k0] = pks_fma(c01i, A1, u);
        v2f t2 = pks_mul(c10r, A0); t2 = pks_fma(c10in, I0, t2);
        t2 = pks_fma(c11r, A1, t2); AR[k1] = pks_fma(c11in, I1, t2);
        v2f u2 = pks_mul(c10r, I0); u2 = pks_fma(c10i, A0, u2);
        u2 = pks_fma(c11r, I1, u2); AI[k1] = pks_fma(c11i, A1, u2);
    }
}

__device__ __forceinline__ void reg_gate_q3_asm(const float* __restrict__ g,
                                                v2f (&AR)[8], v2f (&AI)[8]) {
    const v2f* __restrict__ gp = (const v2f*)g;
    const v2f P0 = gp[18], P1 = gp[19], P1n = gp[20];
    const v2f P2 = gp[21], P3 = gp[22], P3n = gp[23];
#pragma unroll
    for (int k = 0; k < 8; ++k) {
        v2f t = pks_mul_blo(P0, AR[k]);
        t = pks_fma_blo(P1n, AI[k], t);
        t = pks_fma_bhi(P2, AR[k], t);
        v2f nR = pks_fma_bhi(P3n, AI[k], t);
        v2f u = pks_mul_blo(P0, AI[k]);
        u = pks_fma_blo(P1, AR[k], u);
        u = pks_fma_bhi(P2, AI[k], u);
        v2f nI = pks_fma_bhi(P3, AR[k], u);
        AR[k] = nR; AI[k] = nI;
    }
}

template<int LB>
__device__ __forceinline__ void lane_gate_asm(const float* __restrict__ g, int lane,
                                              v2f (&AR)[8], v2f (&AI)[8]) {
    const bool side = (lane >> LB) & 1;
    const float cmr = side ? g[6] : g[0];
    const float cmi = side ? g[7] : g[1];
    const float cmin = side ? g[11] : g[8];
    const float cpr = side ? g[4] : g[2];
    const float cpi = side ? g[5] : g[3];
    const float cpin = side ? g[10] : g[9];
    v2f Cmr; Cmr.x = cmr; Cmr.y = cmr;
    v2f Cmi; Cmi.x = cmi; Cmi.y = cmi;
    v2f Cmin; Cmin.x = cmin; Cmin.y = cmin;
    v2f Cpr; Cpr.x = cpr; Cpr.y = cpr;
    v2f Cpi; Cpi.x = cpi; Cpi.y = cpi;
    v2f Cpin; Cpin.x = cpin; Cpin.y = cpin;
#pragma unroll
    for (int k = 0; k < 8; ++k) {
        v2f PR, PI;
        PR.x = lxor<(1 << LB)>(AR[k].x); PR.y = lxor<(1 << LB)>(AR[k].y);
        PI.x = lxor<(1 << LB)>(AI[k].x); PI.y = lxor<(1 << LB)>(AI[k].y);
        v2f t = pkv_mul(Cmr, AR[k]); t = pkv_fma(Cmin, AI[k], t);
        t = pkv_fma(Cpr, PR, t);     v2f NR = pkv_fma(Cpin, PI, t);
        v2f u = pkv_mul(Cmr, AI[k]); u = pkv_fma(Cmi, AR[k], u);
        u = pkv_fma(Cpr, PI, u);     v2f NI = pkv_fma(Cpi, PR, u);
        AR[k] = NR; AI[k] = NI;
    }
}

template<int HALF>
__device__ __forceinline__ void lane_gate_pl_asm(const float* __restrict__ g,
                                                 v2f (&AR)[8], v2f (&AI)[8]) {
    const v2f* __restrict__ gp = (const v2f*)g;
    const v2f c00r = gp[6],  c00i = gp[7],  c00in = gp[8];
    const v2f c01r = gp[9],  c01i = gp[10], c01in = gp[11];
    const v2f c10r = gp[12], c10i = gp[13], c10in = gp[14];
    const v2f c11r = gp[15], c11i = gp[16], c11in = gp[17];
#pragma unroll
    for (int k0 = 0; k0 < 8; k0 += 2) {
        const int k1 = k0 + 1;
        float Xr0 = AR[k0].x, Xr1 = AR[k0].y, Yr0 = AR[k1].x, Yr1 = AR[k1].y;
        float Xi0 = AI[k0].x, Xi1 = AI[k0].y, Yi0 = AI[k1].x, Yi1 = AI[k1].y;
        swap_pl<HALF>(Xr0, Yr0); swap_pl<HALF>(Xr1, Yr1);
        swap_pl<HALF>(Xi0, Yi0); swap_pl<HALF>(Xi1, Yi1);
        v2f Xr; Xr.x = Xr0; Xr.y = Xr1;  v2f Yr; Yr.x = Yr0; Yr.y = Yr1;
        v2f Xi; Xi.x = Xi0; Xi.y = Xi1;  v2f Yi; Yi.x = Yi0; Yi.y = Yi1;
        v2f t = pks_mul(c00r, Xr); t = pks_fma(c00in, Xi, t);
        t = pks_fma(c01r, Yr, t);  v2f Pr = pks_fma(c01in, Yi, t);
        v2f u = pks_mul(c00r, Xi); u = pks_fma(c00i, Xr, u);
        u = pks_fma(c01r, Yi, u);  v2f Pi = pks_fma(c01i, Yr, u);
        v2f t2 = pks_mul(c10r, Xr); t2 = pks_fma(c10in, Xi, t2);
        t2 = pks_fma(c11r, Yr, t2); v2f Qr = pks_fma(c11in, Yi, t2);
        v2f u2 = pks_mul(c10r, Xi); u2 = pks_fma(c10i, Xr, u2);
        u2 = pks_fma(c11r, Yi, u2); v2f Qi = pks_fma(c11i, Yr, u2);
        float pr0 = Pr.x, pr1 = Pr.y, qr0 = Qr.x, qr1 = Qr.y;
        float pi0 = Pi.x, pi1 = Pi.y, qi0 = Qi.x, qi1 = Qi.y;
        swap_pl<HALF>(pr0, qr0); swap_pl<HALF>(pr1, qr1);
        swap_pl<HALF>(pi0, qi0); swap_pl<HALF>(pi1, qi1);
        AR[k0].x = pr0; AR[k0].y = pr1; AR[k1].x = qr0; AR[k1].y = qr1;
        AI[k0].x = pi0; AI[k0].y = pi1; AI[k1].x = qi0; AI[k1].y = qi1;
    }
}

// ---- compile-time CNOT-ring tables (element index e, 4 bits) ----
constexpr int rr_src(int rs, int e) {
    int s = e;
    for (int i = 3 - rs; i >= 0; --i) s ^= ((s >> (3 - i)) & 1) << (3 - i - rs);
    return s;
}
constexpr int rl_mask(int rs, int e) {
    int m = 0;
    for (int i = (4 - rs < 0 ? 0 : 4 - rs); i <= 3; ++i)
        if ((e >> (3 - i)) & 1) m |= 1 << (9 - i - rs);
    return m;
}

// gate sweep for layer L (10 Rot gates)
template<int L>
__device__ __forceinline__ void do_gates(const float* __restrict__ gt, int lane,
                                         v2f (&AR)[8], v2f (&AI)[8]) {
    const float* __restrict__ gb = gt + L * NQ * GSTRIDE;
    reg_gate_asm<4>(gb + 0 * GSTRIDE, AR, AI);   // qubit0: e-mask 8
    reg_gate_asm<2>(gb + 1 * GSTRIDE, AR, AI);   // qubit1: e-mask 4
    reg_gate_asm<1>(gb + 2 * GSTRIDE, AR, AI);   // qubit2: e-mask 2
    reg_gate_q3_asm(gb + 3 * GSTRIDE, AR, AI);   // qubit3: e-mask 1
    lane_gate_pl_asm<32>(gb + 4 * GSTRIDE, AR, AI);
    lane_gate_pl_asm<16>(gb + 5 * GSTRIDE, AR, AI);
    lane_gate_asm<3>(gb + 6 * GSTRIDE, lane, AR, AI);
    lane_gate_asm<2>(gb + 7 * GSTRIDE, lane, AR, AI);
    lane_gate_asm<1>(gb + 8 * GSTRIDE, lane, AR, AI);
    lane_gate_asm<0>(gb + 9 * GSTRIDE, lane, AR, AI);
}

// CNOT-ring movement for layer L: RR+RL+LL folded into one bpermute gather, then LR
template<int L>
__device__ __forceinline__ void do_move(int lane, v2f (&AR)[8], v2f (&AI)[8]) {
    constexpr int rs = L + 1;
    int y = lane;
#pragma unroll
    for (int i = 9 - rs; i >= 4; --i)
        y ^= ((y >> (9 - i)) & 1) << (9 - i - rs);
    const int base = y << 2;
    {
        float nr[16], ni[16];
#pragma unroll
        for (int e = 0; e < 16; ++e) {
            const int src = rr_src(rs, e);
            const int am  = rl_mask(rs, e) << 2;
            nr[e] = __int_as_float(__builtin_amdgcn_ds_bpermute(base ^ am, __float_as_int(getv(AR, src))));
            ni[e] = __int_as_float(__builtin_amdgcn_ds_bpermute(base ^ am, __float_as_int(getv(AI, src))));
        }
#pragma unroll
        for (int k = 0; k < 8; ++k) {
            AR[k].x = nr[2 * k]; AR[k].y = nr[2 * k + 1];
            AI[k].x = ni[2 * k]; AI[k].y = ni[2 * k + 1];
        }
    }
    // LR: predicated element-pair swaps
#pragma unroll
    for (int i = 10 - rs; i <= 9; ++i) {
        const bool p = (lane >> (9 - i)) & 1;
        const int tm = 1 << (13 - i - rs);
#pragma unroll
        for (int e = 0; e < 16; ++e) {
            if (!(e & tm)) {
                const int e1 = e | tm;
                float v0r = getv(AR, e), v1r = getv(AR, e1);
                setv(AR, e, p ? v1r : v0r); setv(AR, e1, p ? v0r : v1r);
                float v0i = getv(AI, e), v1i = getv(AI, e1);
                setv(AI, e, p ? v1i : v0i); setv(AI, e1, p ? v0i : v1i);
            }
        }
    }
}

__device__ __forceinline__ float ftanh(float s) {
    float e = __expf(2.f * s);
    return 1.f - 2.f / (e + 1.f);
}

// ---------------- prep: gate table (48 floats/gate) + W1 transpose ----------------
// (W1-transpose prep exonerated in r11: the ~42us total-vs-fused gap is fixed
// harness overhead, present with 1-block prep too. Transposed w1t is worth 11us
// in the fused MLP: r10=197 vs r11-direct=208.)
__global__ void prep_kernel(const float* __restrict__ qw, const float* __restrict__ W1,
                            float* __restrict__ gtab, float* __restrict__ w1t) {
    int tid = blockIdx.x * 256 + threadIdx.x;
    if (tid < INFEAT * HID) {
        int c = tid & 127, k = tid >> 7;
        w1t[k * HID + c] = W1[c * INFEAT + k];
    }
    if (blockIdx.x == 0 && threadIdx.x < NL * NQ) {
        int t = threadIdx.x;
        float phi = qw[t * 3 + 0], th = qw[t * 3 + 1], om = qw[t * 3 + 2];
        float c = __cosf(th * 0.5f), s = __sinf(th * 0.5f);
        float a = 0.5f * (phi + om), b = 0.5f * (phi - om);
        float ca = __cosf(a), sa = __sinf(a);
        float cb = __cosf(b), sb = __sinf(b);
        float m00r = ca * c,  m00i = -sa * c;
        float m01r = -cb * s, m01i = -sb * s;
        float m10r = cb * s,  m10i = -sb * s;
        float m11r = ca * c,  m11i = sa * c;
        float* g = gtab + t * GSTRIDE;
        g[0] = m00r; g[1] = m00i; g[2] = m01r; g[3] = m01i;
        g[4] = m10r; g[5] = m10i; g[6] = m11r; g[7] = m11i;
        g[8] = -m00i; g[9] = -m01i; g[10] = -m10i; g[11] = -m11i;
        g[12] = g[13] = m00r;  g[14] = g[15] = m00i;  g[16] = g[17] = -m00i;
        g[18] = g[19] = m01r;  g[20] = g[21] = m01i;  g[22] = g[23] = -m01i;
        g[24] = g[25] = m10r;  g[26] = g[27] = m10i;  g[28] = g[29] = -m10i;
        g[30] = g[31] = m11r;  g[32] = g[33] = m11i;  g[34] = g[35] = -m11i;
        g[36] = m00r;  g[37] = m10r;
        g[38] = m00i;  g[39] = m10i;
        g[40] = -m00i; g[41] = -m10i;
        g[42] = m01r;  g[43] = m11r;
        g[44] = m01i;  g[45] = m11i;
        g[46] = -m01i; g[47] = -m11i;
    }
}

// ---------------- fused kernel: K-split MLP -> circuit -> head ----------------
// NO launch_bounds minimum: (256,6)->40 VGPR/660MB spill (r8), (256,4)->64 VGPR/
// 270MB spill (r9). Plain (256) allocates ~84 VGPR spill-free (r7/r10).
__global__ __launch_bounds__(256) void fused_kernel(
    const float* __restrict__ x, const float* __restrict__ w1t,
    const float* __restrict__ b1, const float* __restrict__ W2,
    const float* __restrict__ b2, const float* __restrict__ gtab,
    const float* __restrict__ W3, const float* __restrict__ b3,
    const float* __restrict__ W4, const float* __restrict__ b4,
    float* __restrict__ out)
{
    __shared__ float w3s[HID * 11];
    __shared__ float b3s[HID], w4s[HID];
    __shared__ float b4s;
    __shared__ v2f hpart[4][4][64];   // [k-slice wave][row][lane(2 cols)]

    const int t = threadIdx.x;
    for (int f = t; f < HID * NQ; f += 256) {
        int c = f / NQ, k = f - c * NQ;
        w3s[c * 11 + k] = W3[f];
    }
    if (t < HID) { b3s[t] = b3[t]; w4s[t] = W4[t]; }
    if (t == 0) b4s = b4[0];

    const int lane = t & 63;
    const int wid = t >> 6;
    const int row0 = blockIdx.x * 4;
    const int ukw = __builtin_amdgcn_readfirstlane(wid);

    // ---- MLP phase 1: partial h for all 4 rows over k-slice (r10-proven form) ----
    v2f acc[4];
#pragma unroll
    for (int r = 0; r < 4; ++r) acc[r] = (v2f)(0.f);
    const float4* __restrict__ xr0 = (const float4*)(x + (size_t)(row0 + 0) * INFEAT + ukw * 64);
    const float4* __restrict__ xr1 = (const float4*)(x + (size_t)(row0 + 1) * INFEAT + ukw * 64);
    const float4* __restrict__ xr2 = (const float4*)(x + (size_t)(row0 + 2) * INFEAT + ukw * 64);
    const float4* __restrict__ xr3 = (const float4*)(x + (size_t)(row0 + 3) * INFEAT + ukw * 64);
    const float2* __restrict__ w1p = (const float2*)w1t + (size_t)ukw * 64 * 64 + lane;
#pragma unroll 4
    for (int kk4 = 0; kk4 < 16; ++kk4) {
        float4 x0 = xr0[kk4], x1 = xr1[kk4], x2 = xr2[kk4], x3 = xr3[kk4];
        float xk[4][4] = {{x0.x, x0.y, x0.z, x0.w}, {x1.x, x1.y, x1.z, x1.w},
                          {x2.x, x2.y, x2.z, x2.w}, {x3.x, x3.y, x3.z, x3.w}};
#pragma unroll
        for (int j = 0; j < 4; ++j) {
            float2 w = w1p[(kk4 * 4 + j) * 64];
            v2f wv; wv.x = w.x; wv.y = w.y;
#pragma unroll
            for (int r = 0; r < 4; ++r) {
                v2f xb; xb.x = xk[r][j]; xb.y = xk[r][j];
                acc[r] = __builtin_elementwise_fma(xb, wv, acc[r]);
            }
        }
    }
#pragma unroll
    for (int r = 0; r < 4; ++r) hpart[wid][r][lane] = acc[r];
    __syncthreads();

    // ---- MLP phase 2 ----
    v2f hs = hpart[0][wid][lane];
    hs += hpart[1][wid][lane];
    hs += hpart[2][wid][lane];
    hs += hpart[3][wid][lane];
    float2 b1v = ((const float2*)b1)[lane];
    float h0 = fmaxf(hs.x + b1v.x, 0.f);
    float h1 = fmaxf(hs.y + b1v.y, 0.f);

    const int row = row0 + wid;

    // ---- angles = tanh(h@W2^T + b2) ----
    float cth[NQ], sth[NQ];
#pragma unroll
    for (int w = 0; w < NQ; ++w) {
        float2 w2v = ((const float2*)(W2 + (size_t)w * HID))[lane];
        float aw = wave_sum(fmaf(h0, w2v.x, h1 * w2v.y)) + b2[w];
        float th = ftanh(aw) * 0.5f;
        cth[w] = __cosf(th); sth[w] = __sinf(th);
    }

    // ---- fused RY + layer-0 Rot: still a product state (no CNOT yet) ----
    // per-qubit complex factors: (alpha,beta) = Rot0_w . (cos, sin)
    float alr[NQ], ali[NQ], ber[NQ], bei[NQ];
#pragma unroll
    for (int w = 0; w < NQ; ++w) {
        const float* __restrict__ g = gtab + w * GSTRIDE;   // layer 0, qubit w
        alr[w] = fmaf(g[0], cth[w], g[2] * sth[w]);
        ali[w] = fmaf(g[1], cth[w], g[3] * sth[w]);
        ber[w] = fmaf(g[4], cth[w], g[6] * sth[w]);
        bei[w] = fmaf(g[5], cth[w], g[7] * sth[w]);
    }
    // lane part: qubits 4..9 (lane bit 9-w)
    float Lr, Li;
    {
        bool b4q = (lane >> 5) & 1;
        Lr = b4q ? ber[4] : alr[4];  Li = b4q ? bei[4] : ali[4];
#pragma unroll
        for (int w = 5; w < 10; ++w) {
            bool bw = (lane >> (9 - w)) & 1;
            float fr = bw ? ber[w] : alr[w], fi = bw ? bei[w] : ali[w];
            float nr = Lr * fr - Li * fi;
            float ni = Lr * fi + Li * fr;
            Lr = nr; Li = ni;
        }
    }
    // element part: qubit w(0..3) <-> e-bit(3-w)
    float q01r[4], q01i[4], q23r[4], q23i[4];
#pragma unroll
    for (int j = 0; j < 4; ++j) {
        float f0r = (j & 2) ? ber[0] : alr[0], f0i = (j & 2) ? bei[0] : ali[0];
        float f1r = (j & 1) ? ber[1] : alr[1], f1i = (j & 1) ? bei[1] : ali[1];
        q01r[j] = f0r * f1r - f0i * f1i;
        q01i[j] = f0r * f1i + f0i * f1r;
        float f2r = (j & 2) ? ber[2] : alr[2], f2i = (j & 2) ? bei[2] : ali[2];
        float f3r = (j & 1) ? ber[3] : alr[3], f3i = (j & 1) ? bei[3] : ali[3];
        q23r[j] = f2r * f3r - f2i * f3i;
        q23i[j] = f2r * f3i + f2i * f3r;
    }
    v2f AR[8], AI[8];
#pragma unroll
    for (int e = 0; e < 16; ++e) {
        const int jh = e >> 2, jl = e & 3;
        float tr = q01r[jh] * q23r[jl] - q01i[jh] * q23i[jl];
        float ti = q01r[jh] * q23i[jl] + q01i[jh] * q23r[jl];
        float ar = tr * Lr - ti * Li;
        float ai = tr * Li + ti * Lr;
        setv(AR, e, ar); setv(AI, e, ai);
    }

    // ---- layer-0 movement, then layers 1..3 (gates + movement) ----
    do_move<0>(lane, AR, AI);
    do_gates<1>(gtab, lane, AR, AI);
    do_move<1>(lane, AR, AI);
    do_gates<2>(gtab, lane, AR, AI);
    do_move<2>(lane, AR, AI);
    do_gates<3>(gtab, lane, AR, AI);
    do_move<3>(lane, AR, AI);

    // ---- Z expectations ----
    v2f Pk[8];
#pragma unroll
    for (int k = 0; k < 8; ++k) Pk[k] = AR[k] * AR[k] + AI[k] * AI[k];
    v2f S = Pk[0] + Pk[1] + Pk[2] + Pk[3] + Pk[4] + Pk[5] + Pk[6] + Pk[7];
    float ptot = S.x + S.y;
    v2f Sq0 = Pk[4] + Pk[5] + Pk[6] + Pk[7];
    v2f Sq1 = Pk[2] + Pk[3] + Pk[6] + Pk[7];
    v2f Sq2 = Pk[1] + Pk[3] + Pk[5] + Pk[7];
    float es0 = wave_sum(ptot - 2.f * (Sq0.x + Sq0.y));
    float es1 = wave_sum(ptot - 2.f * (Sq1.x + Sq1.y));
    float es2 = wave_sum(ptot - 2.f * (Sq2.x + Sq2.y));
    float es3 = wave_sum(ptot - 2.f * S.y);
    // lane-qubit expectations via one Walsh-Hadamard butterfly on ptot
    float Wv = ptot;
    {
        float p;
        p = lxor<1>(Wv);  Wv = (lane & 1)  ? p - Wv : Wv + p;
        p = lxor<2>(Wv);  Wv = (lane & 2)  ? p - Wv : Wv + p;
        p = lxor<4>(Wv);  Wv = (lane & 4)  ? p - Wv : Wv + p;
        p = lxor<8>(Wv);  Wv = (lane & 8)  ? p - Wv : Wv + p;
        p = lxor<16>(Wv); Wv = (lane & 16) ? p - Wv : Wv + p;
        p = lxor<32>(Wv); Wv = (lane & 32) ? p - Wv : Wv + p;
    }
    const int wvi = __float_as_int(Wv);
    float es[NQ];
    es[0] = es0; es[1] = es1; es[2] = es2; es[3] = es3;
    es[4] = __int_as_float(__builtin_amdgcn_readlane(wvi, 32));
    es[5] = __int_as_float(__builtin_amdgcn_readlane(wvi, 16));
    es[6] = __int_as_float(__builtin_amdgcn_readlane(wvi, 8));
    es[7] = __int_as_float(__builtin_amdgcn_readlane(wvi, 4));
    es[8] = __int_as_float(__builtin_amdgcn_readlane(wvi, 2));
    es[9] = __int_as_float(__builtin_amdgcn_readlane(wvi, 1));

    // ---- head ----
    float accv = 0.f;
#pragma unroll
    for (int j = 0; j < 2; ++j) {
        int c = lane + 64 * j;
        float d = b3s[c];
#pragma unroll
        for (int k = 0; k < NQ; ++k) d = fmaf(w3s[c * 11 + k], es[k], d);
        d = fmaxf(d, 0.f);
        accv = fmaf(d, w4s[c], accv);
    }
    accv = wave_sum(accv);
    if (lane == 0) out[row] = accv + b4s;
}

extern "C" void kernel_launch(void* const* d_in, const int* in_sizes, int n_in,
                              void* d_out, int out_size, void* d_ws, size_t ws_size,
                              hipStream_t stream) {
    const float* x  = (const float*)d_in[0];
    const float* W1 = (const float*)d_in[1];
    const float* b1 = (const float*)d_in[2];
    const float* W2 = (const float*)d_in[3];
    const float* b2 = (const float*)d_in[4];
    const float* qw = (const float*)d_in[5];
    const float* W3 = (const float*)d_in[6];
    const float* b3 = (const float*)d_in[7];
    const float* W4 = (const float*)d_in[8];
    const float* b4 = (const float*)d_in[9];
    float* gtab = (float*)d_ws;                 // 40*48 = 1920 floats
    float* w1t  = (float*)d_ws + 2048;          // 32768 floats
    float* out  = (float*)d_out;

    prep_kernel<<<(INFEAT * HID + 255) / 256, 256, 0, stream>>>(qw, W1, gtab, w1t);
    fused_kernel<<<BATCH / 4, 256, 0, stream>>>(x, w1t, b1, W2, b2, gtab, W3, b3, W4, b4, out);
}

// Round 13
// 219.674 us; speedup vs baseline: 1.1407x; 1.0218x over previous
//
#include <hip/hip_runtime.h>
#include <math.h>

#define BATCH 16384
#define INFEAT 256
#define HID 128
#define NQ 10
#define NL 4
#define GSTRIDE 48   // floats per gate in gtab

typedef float v2f __attribute__((ext_vector_type(2)));

// ---------- cross-lane xor helper: DPP for 1,2,3,8; ds_swizzle for <32; shfl for 32+ ----------
template<int M>
__device__ __forceinline__ float lxor(float x) {
    if constexpr (M == 0) {
        return x;
    } else if constexpr (M < 4) {
        constexpr int ctrl = (0 ^ M) | ((1 ^ M) << 2) | ((2 ^ M) << 4) | ((3 ^ M) << 6);
        return __int_as_float(__builtin_amdgcn_update_dpp(
            __float_as_int(x), __float_as_int(x), ctrl, 0xF, 0xF, false));
    } else if constexpr (M == 8) {
        return __int_as_float(__builtin_amdgcn_update_dpp(
            __float_as_int(x), __float_as_int(x), 0x128, 0xF, 0xF, false));  // ROW_ROR:8
    } else if constexpr (M < 32) {
        return __int_as_float(__builtin_amdgcn_ds_swizzle(
            __float_as_int(x), (M << 10) | 0x1F));
    } else {
        return __shfl_xor(x, M, 64);
    }
}

// full 64-lane sum — proven lxor ladder (permlane-swap on same-SSA copies miscompiles; r5)
__device__ __forceinline__ float wave_sum(float v) {
    v += lxor<1>(v); v += lxor<2>(v); v += lxor<8>(v);
    v += lxor<4>(v); v += lxor<16>(v); v += lxor<32>(v);
    return v;
}

// gfx950 VALU cross-lane exchange; a and b MUST be distinct SSA values.
template<int HALF>
__device__ __forceinline__ void swap_pl(float& a, float& b) {
    if constexpr (HALF == 32)
        asm("v_permlane32_swap_b32 %0, %1" : "+v"(a), "+v"(b));
    else
        asm("v_permlane16_swap_b32 %0, %1" : "+v"(a), "+v"(b));
}

// ---------- explicit VOP3P packed-f32 helpers ----------
__device__ __forceinline__ v2f pks_mul(v2f c, v2f a) {
    v2f d; asm("v_pk_mul_f32 %0, %1, %2" : "=v"(d) : "s"(c), "v"(a)); return d;
}
__device__ __forceinline__ v2f pks_fma(v2f c, v2f a, v2f b) {
    v2f d; asm("v_pk_fma_f32 %0, %1, %2, %3" : "=v"(d) : "s"(c), "v"(a), "v"(b)); return d;
}
// v-coefficient with LOW-half broadcast (coefficient pair's .y never read -> no splat mov)
__device__ __forceinline__ v2f pkv_mul_c(v2f c, v2f a) {
    v2f d; asm("v_pk_mul_f32 %0, %1, %2 op_sel:[0,0] op_sel_hi:[0,1]"
               : "=v"(d) : "v"(c), "v"(a)); return d;
}
__device__ __forceinline__ v2f pkv_fma_c(v2f c, v2f a, v2f b) {
    v2f d; asm("v_pk_fma_f32 %0, %1, %2, %3 op_sel:[0,0,0] op_sel_hi:[0,1,1]"
               : "=v"(d) : "v"(c), "v"(a), "v"(b)); return d;
}
// q3 variants: src1 broadcast from its LOW or HIGH 32-bit half via op_sel
__device__ __forceinline__ v2f pks_mul_blo(v2f c, v2f a) {
    v2f d; asm("v_pk_mul_f32 %0, %1, %2 op_sel:[0,0] op_sel_hi:[1,0]"
               : "=v"(d) : "s"(c), "v"(a)); return d;
}
__device__ __forceinline__ v2f pks_fma_blo(v2f c, v2f a, v2f b) {
    v2f d; asm("v_pk_fma_f32 %0, %1, %2, %3 op_sel:[0,0,0] op_sel_hi:[1,0,1]"
               : "=v"(d) : "s"(c), "v"(a), "v"(b)); return d;
}
__device__ __forceinline__ v2f pks_fma_bhi(v2f c, v2f a, v2f b) {
    v2f d; asm("v_pk_fma_f32 %0, %1, %2, %3 op_sel:[0,1,0] op_sel_hi:[1,1,1]"
               : "=v"(d) : "s"(c), "v"(a), "v"(b)); return d;
}

// ---- state: v2f AR[8], AI[8]; element e = 2k+h; qubit w(0..3) <-> e-bit(3-w);
// ---- qubits 4..9 <-> lane bits 5..0.
__device__ __forceinline__ float getv(const v2f (&A)[8], int e) {
    return (e & 1) ? A[e >> 1].y : A[e >> 1].x;
}
__device__ __forceinline__ void setv(v2f (&A)[8], int e, float v) {
    if (e & 1) A[e >> 1].y = v; else A[e >> 1].x = v;
}

// gate table layout (48 floats):
// [0..7]  scalars m00r,m00i,m01r,m01i,m10r,m10i,m11r,m11i
// [8..11] negated scalars -m00i,-m01i,-m10i,-m11i
// [12..35] splat pairs c00r,c00i,c00in,c01r,c01i,c01in,c10r,c10i,c10in,c11r,c11i,c11in
// [36..47] q3 pairs P0,P1,P1n,P2,P3,P3n

template<int KM>
__device__ __forceinline__ void reg_gate_asm(const float* __restrict__ g,
                                             v2f (&AR)[8], v2f (&AI)[8]) {
    const v2f* __restrict__ gp = (const v2f*)g;
    const v2f c00r = gp[6],  c00i = gp[7],  c00in = gp[8];
    const v2f c01r = gp[9],  c01i = gp[10], c01in = gp[11];
    const v2f c10r = gp[12], c10i = gp[13], c10in = gp[14];
    const v2f c11r = gp[15], c11i = gp[16], c11in = gp[17];
#pragma unroll
    for (int k0 = 0; k0 < 8; ++k0) {
        if (k0 & KM) continue;
        const int k1 = k0 | KM;
        v2f A0 = AR[k0], I0 = AI[k0], A1 = AR[k1], I1 = AI[k1];
        v2f t = pks_mul(c00r, A0); t = pks_fma(c00in, I0, t);
        t = pks_fma(c01r, A1, t);  AR[k0] = pks_fma(c01in, I1, t);
        v2f u = pks_mul(c00r, I0); u = pks_fma(c00i, A0, u);
        u = pks_fma(c01r, I1, u);  AI[k0] = pks_fma(c01i, A1, u);
        v2f t2 = pks_mul(c10r, A0); t2 = pks_fma(c10in, I0, t2);
        t2 = pks_fma(c11r, A1, t2); AR[k1] = pks_fma(c11in, I1, t2);
        v2f u2 = pks_mul(c10r, I0); u2 = pks_fma(c10i, A0, u2);
        u2 = pks_fma(c11r, I1, u2); AI[k1] = pks_fma(c11i, A1, u2);
    }
}

__device__ __forceinline__ void reg_gate_q3_asm(const float* __restrict__ g,
                                                v2f (&AR)[8], v2f (&AI)[8]) {
    const v2f* __restrict__ gp = (const v2f*)g;
    const v2f P0 = gp[18], P1 = gp[19], P1n = gp[20];
    const v2f P2 = gp[21], P3 = gp[22], P3n = gp[23];
#pragma unroll
    for (int k = 0; k < 8; ++k) {
        v2f t = pks_mul_blo(P0, AR[k]);
        t = pks_fma_blo(P1n, AI[k], t);
        t = pks_fma_bhi(P2, AR[k], t);
        v2f nR = pks_fma_bhi(P3n, AI[k], t);
        v2f u = pks_mul_blo(P0, AI[k]);
        u = pks_fma_blo(P1, AR[k], u);
        u = pks_fma_bhi(P2, AI[k], u);
        v2f nI = pks_fma_bhi(P3, AR[k], u);
        AR[k] = nR; AI[k] = nI;
    }
}

template<int LB>
__device__ __forceinline__ void lane_gate_asm(const float* __restrict__ g, int lane,
                                              v2f (&AR)[8], v2f (&AI)[8]) {
    const bool side = (lane >> LB) & 1;
    // coefficient pairs: only .x written; pkv_*_c broadcast low half (no splat movs)
    v2f Cmr, Cmi, Cmin, Cpr, Cpi, Cpin;
    Cmr.x  = side ? g[6]  : g[0];
    Cmi.x  = side ? g[7]  : g[1];
    Cmin.x = side ? g[11] : g[8];
    Cpr.x  = side ? g[4]  : g[2];
    Cpi.x  = side ? g[5]  : g[3];
    Cpin.x = side ? g[10] : g[9];
#pragma unroll
    for (int k = 0; k < 8; ++k) {
        v2f PR, PI;
        PR.x = lxor<(1 << LB)>(AR[k].x); PR.y = lxor<(1 << LB)>(AR[k].y);
        PI.x = lxor<(1 << LB)>(AI[k].x); PI.y = lxor<(1 << LB)>(AI[k].y);
        v2f t = pkv_mul_c(Cmr, AR[k]); t = pkv_fma_c(Cmin, AI[k], t);
        t = pkv_fma_c(Cpr, PR, t);     v2f NR = pkv_fma_c(Cpin, PI, t);
        v2f u = pkv_mul_c(Cmr, AI[k]); u = pkv_fma_c(Cmi, AR[k], u);
        u = pkv_fma_c(Cpr, PI, u);     v2f NI = pkv_fma_c(Cpi, PR, u);
        AR[k] = NR; AI[k] = NI;
    }
}

template<int HALF>
__device__ __forceinline__ void lane_gate_pl_asm(const float* __restrict__ g,
                                                 v2f (&AR)[8], v2f (&AI)[8]) {
    const v2f* __restrict__ gp = (const v2f*)g;
    const v2f c00r = gp[6],  c00i = gp[7],  c00in = gp[8];
    const v2f c01r = gp[9],  c01i = gp[10], c01in = gp[11];
    const v2f c10r = gp[12], c10i = gp[13], c10in = gp[14];
    const v2f c11r = gp[15], c11i = gp[16], c11in = gp[17];
#pragma unroll
    for (int k0 = 0; k0 < 8; k0 += 2) {
        const int k1 = k0 + 1;
        float Xr0 = AR[k0].x, Xr1 = AR[k0].y, Yr0 = AR[k1].x, Yr1 = AR[k1].y;
        float Xi0 = AI[k0].x, Xi1 = AI[k0].y, Yi0 = AI[k1].x, Yi1 = AI[k1].y;
        swap_pl<HALF>(Xr0, Yr0); swap_pl<HALF>(Xr1, Yr1);
        swap_pl<HALF>(Xi0, Yi0); swap_pl<HALF>(Xi1, Yi1);
        v2f Xr; Xr.x = Xr0; Xr.y = Xr1;  v2f Yr; Yr.x = Yr0; Yr.y = Yr1;
        v2f Xi; Xi.x = Xi0; Xi.y = Xi1;  v2f Yi; Yi.x = Yi0; Yi.y = Yi1;
        v2f t = pks_mul(c00r, Xr); t = pks_fma(c00in, Xi, t);
        t = pks_fma(c01r, Yr, t);  v2f Pr = pks_fma(c01in, Yi, t);
        v2f u = pks_mul(c00r, Xi); u = pks_fma(c00i, Xr, u);
        u = pks_fma(c01r, Yi, u);  v2f Pi = pks_fma(c01i, Yr, u);
        v2f t2 = pks_mul(c10r, Xr); t2 = pks_fma(c10in, Xi, t2);
        t2 = pks_fma(c11r, Yr, t2); v2f Qr = pks_fma(c11in, Yi, t2);
        v2f u2 = pks_mul(c10r, Xi); u2 = pks_fma(c10i, Xr, u2);
        u2 = pks_fma(c11r, Yi, u2); v2f Qi = pks_fma(c11i, Yr, u2);
        float pr0 = Pr.x, pr1 = Pr.y, qr0 = Qr.x, qr1 = Qr.y;
        float pi0 = Pi.x, pi1 = Pi.y, qi0 = Qi.x, qi1 = Qi.y;
        swap_pl<HALF>(pr0, qr0); swap_pl<HALF>(pr1, qr1);
        swap_pl<HALF>(pi0, qi0); swap_pl<HALF>(pi1, qi1);
        AR[k0].x = pr0; AR[k0].y = pr1; AR[k1].x = qr0; AR[k1].y = qr1;
        AI[k0].x = pi0; AI[k0].y = pi1; AI[k1].x = qi0; AI[k1].y = qi1;
    }
}

// ---- compile-time CNOT-ring tables (element index e, 4 bits) ----
constexpr int rr_src(int rs, int e) {
    int s = e;
    for (int i = 3 - rs; i >= 0; --i) s ^= ((s >> (3 - i)) & 1) << (3 - i - rs);
    return s;
}
constexpr int rl_mask(int rs, int e) {
    int m = 0;
    for (int i = (4 - rs < 0 ? 0 : 4 - rs); i <= 3; ++i)
        if ((e >> (3 - i)) & 1) m |= 1 << (9 - i - rs);
    return m;
}

// gate sweep for layer L (10 Rot gates)
template<int L>
__device__ __forceinline__ void do_gates(const float* __restrict__ gt, int lane,
                                         v2f (&AR)[8], v2f (&AI)[8]) {
    const float* __restrict__ gb = gt + L * NQ * GSTRIDE;
    reg_gate_asm<4>(gb + 0 * GSTRIDE, AR, AI);   // qubit0: e-mask 8
    reg_gate_asm<2>(gb + 1 * GSTRIDE, AR, AI);   // qubit1: e-mask 4
    reg_gate_asm<1>(gb + 2 * GSTRIDE, AR, AI);   // qubit2: e-mask 2
    reg_gate_q3_asm(gb + 3 * GSTRIDE, AR, AI);   // qubit3: e-mask 1
    lane_gate_pl_asm<32>(gb + 4 * GSTRIDE, AR, AI);
    lane_gate_pl_asm<16>(gb + 5 * GSTRIDE, AR, AI);
    lane_gate_asm<3>(gb + 6 * GSTRIDE, lane, AR, AI);
    lane_gate_asm<2>(gb + 7 * GSTRIDE, lane, AR, AI);
    lane_gate_asm<1>(gb + 8 * GSTRIDE, lane, AR, AI);
    lane_gate_asm<0>(gb + 9 * GSTRIDE, lane, AR, AI);
}

// CNOT-ring movement for layer L: RR+RL+LL folded into one bpermute gather, then LR
template<int L>
__device__ __forceinline__ void do_move(int lane, v2f (&AR)[8], v2f (&AI)[8]) {
    constexpr int rs = L + 1;
    int y = lane;
#pragma unroll
    for (int i = 9 - rs; i >= 4; --i)
        y ^= ((y >> (9 - i)) & 1) << (9 - i - rs);
    const int base = y << 2;
    {
        float nr[16], ni[16];
#pragma unroll
        for (int e = 0; e < 16; ++e) {
            const int src = rr_src(rs, e);
            const int am  = rl_mask(rs, e) << 2;
            nr[e] = __int_as_float(__builtin_amdgcn_ds_bpermute(base ^ am, __float_as_int(getv(AR, src))));
            ni[e] = __int_as_float(__builtin_amdgcn_ds_bpermute(base ^ am, __float_as_int(getv(AI, src))));
        }
#pragma unroll
        for (int k = 0; k < 8; ++k) {
            AR[k].x = nr[2 * k]; AR[k].y = nr[2 * k + 1];
            AI[k].x = ni[2 * k]; AI[k].y = ni[2 * k + 1];
        }
    }
    // LR: predicated element-pair swaps
#pragma unroll
    for (int i = 10 - rs; i <= 9; ++i) {
        const bool p = (lane >> (9 - i)) & 1;
        const int tm = 1 << (13 - i - rs);
#pragma unroll
        for (int e = 0; e < 16; ++e) {
            if (!(e & tm)) {
                const int e1 = e | tm;
                float v0r = getv(AR, e), v1r = getv(AR, e1);
                setv(AR, e, p ? v1r : v0r); setv(AR, e1, p ? v0r : v1r);
                float v0i = getv(AI, e), v1i = getv(AI, e1);
                setv(AI, e, p ? v1i : v0i); setv(AI, e1, p ? v0i : v1i);
            }
        }
    }
}

__device__ __forceinline__ float ftanh(float s) {
    float e = __expf(2.f * s);
    return 1.f - 2.f / (e + 1.f);
}

// ---------------- prep: gate table (48 floats/gate) + W1 transpose ----------------
__global__ void prep_kernel(const float* __restrict__ qw, const float* __restrict__ W1,
                            float* __restrict__ gtab, float* __restrict__ w1t) {
    int tid = blockIdx.x * 256 + threadIdx.x;
    if (tid < INFEAT * HID) {
        int c = tid & 127, k = tid >> 7;
        w1t[k * HID + c] = W1[c * INFEAT + k];
    }
    if (blockIdx.x == 0 && threadIdx.x < NL * NQ) {
        int t = threadIdx.x;
        float phi = qw[t * 3 + 0], th = qw[t * 3 + 1], om = qw[t * 3 + 2];
        float c = __cosf(th * 0.5f), s = __sinf(th * 0.5f);
        float a = 0.5f * (phi + om), b = 0.5f * (phi - om);
        float ca = __cosf(a), sa = __sinf(a);
        float cb = __cosf(b), sb = __sinf(b);
        float m00r = ca * c,  m00i = -sa * c;
        float m01r = -cb * s, m01i = -sb * s;
        float m10r = cb * s,  m10i = -sb * s;
        float m11r = ca * c,  m11i = sa * c;
        float* g = gtab + t * GSTRIDE;
        g[0] = m00r; g[1] = m00i; g[2] = m01r; g[3] = m01i;
        g[4] = m10r; g[5] = m10i; g[6] = m11r; g[7] = m11i;
        g[8] = -m00i; g[9] = -m01i; g[10] = -m10i; g[11] = -m11i;
        g[12] = g[13] = m00r;  g[14] = g[15] = m00i;  g[16] = g[17] = -m00i;
        g[18] = g[19] = m01r;  g[20] = g[21] = m01i;  g[22] = g[23] = -m01i;
        g[24] = g[25] = m10r;  g[26] = g[27] = m10i;  g[28] = g[29] = -m10i;
        g[30] = g[31] = m11r;  g[32] = g[33] = m11i;  g[34] = g[35] = -m11i;
        g[36] = m00r;  g[37] = m10r;
        g[38] = m00i;  g[39] = m10i;
        g[40] = -m00i; g[41] = -m10i;
        g[42] = m01r;  g[43] = m11r;
        g[44] = m01i;  g[45] = m11i;
        g[46] = -m01i; g[47] = -m11i;
    }
}

// ---------------- fused kernel: K-split MLP -> circuit -> head ----------------
// (256,4) caps VGPR at 64 (r9 evidence) -> 32 waves/CU (the 64-VGPR occupancy
// cliff). r12's plain build needed 68; the init restructure below drops peak
// live range so 64 fits. TRIPWIRE: WRITE_SIZE >> 1 MB means spills returned.
__global__ __launch_bounds__(256, 4) void fused_kernel(
    const float* __restrict__ x, const float* __restrict__ w1t,
    const float* __restrict__ b1, const float* __restrict__ W2,
    const float* __restrict__ b2, const float* __restrict__ gtab,
    const float* __restrict__ W3, const float* __restrict__ b3,
    const float* __restrict__ W4, const float* __restrict__ b4,
    float* __restrict__ out)
{
    __shared__ float w3s[HID * 11];
    __shared__ float b3s[HID], w4s[HID];
    __shared__ float b4s;
    __shared__ v2f hpart[4][4][64];   // [k-slice wave][row][lane(2 cols)]

    const int t = threadIdx.x;
    for (int f = t; f < HID * NQ; f += 256) {
        int c = f / NQ, k = f - c * NQ;
        w3s[c * 11 + k] = W3[f];
    }
    if (t < HID) { b3s[t] = b3[t]; w4s[t] = W4[t]; }
    if (t == 0) b4s = b4[0];

    const int lane = t & 63;
    const int wid = t >> 6;
    const int row0 = blockIdx.x * 4;
    const int ukw = __builtin_amdgcn_readfirstlane(wid);

    // ---- MLP phase 1: partial h for all 4 rows over k-slice (r10-proven form) ----
    v2f acc[4];
#pragma unroll
    for (int r = 0; r < 4; ++r) acc[r] = (v2f)(0.f);
    const float4* __restrict__ xr0 = (const float4*)(x + (size_t)(row0 + 0) * INFEAT + ukw * 64);
    const float4* __restrict__ xr1 = (const float4*)(x + (size_t)(row0 + 1) * INFEAT + ukw * 64);
    const float4* __restrict__ xr2 = (const float4*)(x + (size_t)(row0 + 2) * INFEAT + ukw * 64);
    const float4* __restrict__ xr3 = (const float4*)(x + (size_t)(row0 + 3) * INFEAT + ukw * 64);
    const float2* __restrict__ w1p = (const float2*)w1t + (size_t)ukw * 64 * 64 + lane;
#pragma unroll 4
    for (int kk4 = 0; kk4 < 16; ++kk4) {
        float4 x0 = xr0[kk4], x1 = xr1[kk4], x2 = xr2[kk4], x3 = xr3[kk4];
        float xk[4][4] = {{x0.x, x0.y, x0.z, x0.w}, {x1.x, x1.y, x1.z, x1.w},
                          {x2.x, x2.y, x2.z, x2.w}, {x3.x, x3.y, x3.z, x3.w}};
#pragma unroll
        for (int j = 0; j < 4; ++j) {
            float2 w = w1p[(kk4 * 4 + j) * 64];
            v2f wv; wv.x = w.x; wv.y = w.y;
#pragma unroll
            for (int r = 0; r < 4; ++r) {
                v2f xb; xb.x = xk[r][j]; xb.y = xk[r][j];
                acc[r] = __builtin_elementwise_fma(xb, wv, acc[r]);
            }
        }
    }
#pragma unroll
    for (int r = 0; r < 4; ++r) hpart[wid][r][lane] = acc[r];
    __syncthreads();

    // ---- MLP phase 2 ----
    v2f hs = hpart[0][wid][lane];
    hs += hpart[1][wid][lane];
    hs += hpart[2][wid][lane];
    hs += hpart[3][wid][lane];
    float2 b1v = ((const float2*)b1)[lane];
    float h0 = fmaxf(hs.x + b1v.x, 0.f);
    float h1 = fmaxf(hs.y + b1v.y, 0.f);

    const int row = row0 + wid;

    // ---- angles = tanh(h@W2^T + b2) ----
    float cth[NQ], sth[NQ];
#pragma unroll
    for (int w = 0; w < NQ; ++w) {
        float2 w2v = ((const float2*)(W2 + (size_t)w * HID))[lane];
        float aw = wave_sum(fmaf(h0, w2v.x, h1 * w2v.y)) + b2[w];
        float th = ftanh(aw) * 0.5f;
        cth[w] = __cosf(th); sth[w] = __sinf(th);
    }

    // ---- fused RY + layer-0 Rot product state (low-pressure construction) ----
    // lane qubits 4..9: factors consumed immediately into running product (Lr,Li)
    float Lr, Li;
    {
        const float* __restrict__ g = gtab + 4 * GSTRIDE;
        bool bw = (lane >> 5) & 1;
        float g0 = bw ? g[4] : g[0], g1 = bw ? g[5] : g[1];
        float g2 = bw ? g[6] : g[2], g3 = bw ? g[7] : g[3];
        Lr = fmaf(g0, cth[4], g2 * sth[4]);
        Li = fmaf(g1, cth[4], g3 * sth[4]);
    }
#pragma unroll
    for (int w = 5; w < 10; ++w) {
        const float* __restrict__ g = gtab + w * GSTRIDE;
        bool bw = (lane >> (9 - w)) & 1;
        float g0 = bw ? g[4] : g[0], g1 = bw ? g[5] : g[1];
        float g2 = bw ? g[6] : g[2], g3 = bw ? g[7] : g[3];
        float fr = fmaf(g0, cth[w], g2 * sth[w]);
        float fi = fmaf(g1, cth[w], g3 * sth[w]);
        float nr = Lr * fr - Li * fi;
        float ni = Lr * fi + Li * fr;
        Lr = nr; Li = ni;
    }
    // element qubits 0..3 in two scoped blocks (factor scalars die at block exit)
    float q01r[4], q01i[4], q23r[4], q23i[4];
    {
        const float* __restrict__ ga = gtab + 0 * GSTRIDE;
        const float* __restrict__ gb = gtab + 1 * GSTRIDE;
        float a0r = fmaf(ga[0], cth[0], ga[2] * sth[0]);
        float a0i = fmaf(ga[1], cth[0], ga[3] * sth[0]);
        float b0r = fmaf(ga[4], cth[0], ga[6] * sth[0]);
        float b0i = fmaf(ga[5], cth[0], ga[7] * sth[0]);
        float a1r = fmaf(gb[0], cth[1], gb[2] * sth[1]);
        float a1i = fmaf(gb[1], cth[1], gb[3] * sth[1]);
        float b1r = fmaf(gb[4], cth[1], gb[6] * sth[1]);
        float b1i = fmaf(gb[5], cth[1], gb[7] * sth[1]);
#pragma unroll
        for (int j = 0; j < 4; ++j) {
            float f0r = (j & 2) ? b0r : a0r, f0i = (j & 2) ? b0i : a0i;
            float f1r = (j & 1) ? b1r : a1r, f1i = (j & 1) ? b1i : a1i;
            q01r[j] = f0r * f1r - f0i * f1i;
            q01i[j] = f0r * f1i + f0i * f1r;
        }
    }
    {
        const float* __restrict__ ga = gtab + 2 * GSTRIDE;
        const float* __restrict__ gb = gtab + 3 * GSTRIDE;
        float a2r = fmaf(ga[0], cth[2], ga[2] * sth[2]);
        float a2i = fmaf(ga[1], cth[2], ga[3] * sth[2]);
        float b2r = fmaf(ga[4], cth[2], ga[6] * sth[2]);
        float b2i = fmaf(ga[5], cth[2], ga[7] * sth[2]);
        float a3r = fmaf(gb[0], cth[3], gb[2] * sth[3]);
        float a3i = fmaf(gb[1], cth[3], gb[3] * sth[3]);
        float b3r = fmaf(gb[4], cth[3], gb[6] * sth[3]);
        float b3i = fmaf(gb[5], cth[3], gb[7] * sth[3]);
#pragma unroll
        for (int j = 0; j < 4; ++j) {
            float f2r = (j & 2) ? b2r : a2r, f2i = (j & 2) ? b2i : a2i;
            float f3r = (j & 1) ? b3r : a3r, f3i = (j & 1) ? b3i : a3i;
            q23r[j] = f2r * f3r - f2i * f3i;
            q23i[j] = f2r * f3i + f2i * f3r;
        }
    }
    v2f AR[8], AI[8];
#pragma unroll
    for (int e = 0; e < 16; ++e) {
        const int jh = e >> 2, jl = e & 3;
        float tr = q01r[jh] * q23r[jl] - q01i[jh] * q23i[jl];
        float ti = q01r[jh] * q23i[jl] + q01i[jh] * q23r[jl];
        float ar = tr * Lr - ti * Li;
        float ai = tr * Li + ti * Lr;
        setv(AR, e, ar); setv(AI, e, ai);
    }

    // ---- layer-0 movement, then layers 1..3 (gates + movement) ----
    do_move<0>(lane, AR, AI);
    do_gates<1>(gtab, lane, AR, AI);
    do_move<1>(lane, AR, AI);
    do_gates<2>(gtab, lane, AR, AI);
    do_move<2>(lane, AR, AI);
    do_gates<3>(gtab, lane, AR, AI);
    do_move<3>(lane, AR, AI);

    // ---- Z expectations ----
    v2f Pk[8];
#pragma unroll
    for (int k = 0; k < 8; ++k) Pk[k] = AR[k] * AR[k] + AI[k] * AI[k];
    v2f S = Pk[0] + Pk[1] + Pk[2] + Pk[3] + Pk[4] + Pk[5] + Pk[6] + Pk[7];
    float ptot = S.x + S.y;
    v2f Sq0 = Pk[4] + Pk[5] + Pk[6] + Pk[7];
    v2f Sq1 = Pk[2] + Pk[3] + Pk[6] + Pk[7];
    v2f Sq2 = Pk[1] + Pk[3] + Pk[5] + Pk[7];
    float es0 = wave_sum(ptot - 2.f * (Sq0.x + Sq0.y));
    float es1 = wave_sum(ptot - 2.f * (Sq1.x + Sq1.y));
    float es2 = wave_sum(ptot - 2.f * (Sq2.x + Sq2.y));
    float es3 = wave_sum(ptot - 2.f * S.y);
    // lane-qubit expectations via one Walsh-Hadamard butterfly on ptot
    float Wv = ptot;
    {
        float p;
        p = lxor<1>(Wv);  Wv = (lane & 1)  ? p - Wv : Wv + p;
        p = lxor<2>(Wv);  Wv = (lane & 2)  ? p - Wv : Wv + p;
        p = lxor<4>(Wv);  Wv = (lane & 4)  ? p - Wv : Wv + p;
        p = lxor<8>(Wv);  Wv = (lane & 8)  ? p - Wv : Wv + p;
        p = lxor<16>(Wv); Wv = (lane & 16) ? p - Wv : Wv + p;
        p = lxor<32>(Wv); Wv = (lane & 32) ? p - Wv : Wv + p;
    }
    const int wvi = __float_as_int(Wv);
    float es[NQ];
    es[0] = es0; es[1] = es1; es[2] = es2; es[3] = es3;
    es[4] = __int_as_float(__builtin_amdgcn_readlane(wvi, 32));
    es[5] = __int_as_float(__builtin_amdgcn_readlane(wvi, 16));
    es[6] = __int_as_float(__builtin_amdgcn_readlane(wvi, 8));
    es[7] = __int_as_float(__builtin_amdgcn_readlane(wvi, 4));
    es[8] = __int_as_float(__builtin_amdgcn_readlane(wvi, 2));
    es[9] = __int_as_float(__builtin_amdgcn_readlane(wvi, 1));

    // ---- head ----
    float accv = 0.f;
#pragma unroll
    for (int j = 0; j < 2; ++j) {
        int c = lane + 64 * j;
        float d = b3s[c];
#pragma unroll
        for (int k = 0; k < NQ; ++k) d = fmaf(w3s[c * 11 + k], es[k], d);
        d = fmaxf(d, 0.f);
        accv = fmaf(d, w4s[c], accv);
    }
    accv = wave_sum(accv);
    if (lane == 0) out[row] = accv + b4s;
}

extern "C" void kernel_launch(void* const* d_in, const int* in_sizes, int n_in,
                              void* d_out, int out_size, void* d_ws, size_t ws_size,
                              hipStream_t stream) {
    const float* x  = (const float*)d_in[0];
    const float* W1 = (const float*)d_in[1];
    const float* b1 = (const float*)d_in[2];
    const float* W2 = (const float*)d_in[3];
    const float* b2 = (const float*)d_in[4];
    const float* qw = (const float*)d_in[5];
    const float* W3 = (const float*)d_in[6];
    const float* b3 = (const float*)d_in[7];
    const float* W4 = (const float*)d_in[8];
    const float* b4 = (const float*)d_in[9];
    float* gtab = (float*)d_ws;                 // 40*48 = 1920 floats
    float* w1t  = (float*)d_ws + 2048;          // 32768 floats
    float* out  = (float*)d_out;

    prep_kernel<<<(INFEAT * HID + 255) / 256, 256, 0, stream>>>(qw, W1, gtab, w1t);
    fused_kernel<<<BATCH / 4, 256, 0, stream>>>(x, w1t, b1, W2, b2, gtab, W3, b3, W4, b4, out);
}

// Round 14
// 216.482 us; speedup vs baseline: 1.1575x; 1.0147x over previous
//
#include <hip/hip_runtime.h>
#include <math.h>

#define BATCH 16384
#define INFEAT 256
#define HID 128
#define NQ 10
#define NL 4
#define GSTRIDE 48   // floats per gate in gtab

typedef float v2f __attribute__((ext_vector_type(2)));

// ---------- cross-lane xor helper: DPP for 1,2,3,8; ds_swizzle for <32; shfl for 32+ ----------
template<int M>
__device__ __forceinline__ float lxor(float x) {
    if constexpr (M == 0) {
        return x;
    } else if constexpr (M < 4) {
        constexpr int ctrl = (0 ^ M) | ((1 ^ M) << 2) | ((2 ^ M) << 4) | ((3 ^ M) << 6);
        return __int_as_float(__builtin_amdgcn_update_dpp(
            __float_as_int(x), __float_as_int(x), ctrl, 0xF, 0xF, false));
    } else if constexpr (M == 8) {
        return __int_as_float(__builtin_amdgcn_update_dpp(
            __float_as_int(x), __float_as_int(x), 0x128, 0xF, 0xF, false));  // ROW_ROR:8
    } else if constexpr (M < 32) {
        return __int_as_float(__builtin_amdgcn_ds_swizzle(
            __float_as_int(x), (M << 10) | 0x1F));
    } else {
        return __shfl_xor(x, M, 64);
    }
}

// full 64-lane sum, pure-VALU DPP chain (row_shr 1/2/4/8 + row_bcast 15/31),
// result broadcast via readlane(63). Replaces the lxor ladder's 3 DS ops/call.
__device__ __forceinline__ float dpp_sum(float v) {
    v += __int_as_float(__builtin_amdgcn_update_dpp(0, __float_as_int(v), 0x111, 0xF, 0xF, true));
    v += __int_as_float(__builtin_amdgcn_update_dpp(0, __float_as_int(v), 0x112, 0xF, 0xF, true));
    v += __int_as_float(__builtin_amdgcn_update_dpp(0, __float_as_int(v), 0x114, 0xF, 0xF, true));
    v += __int_as_float(__builtin_amdgcn_update_dpp(0, __float_as_int(v), 0x118, 0xF, 0xF, true));
    v += __int_as_float(__builtin_amdgcn_update_dpp(0, __float_as_int(v), 0x142, 0xF, 0xF, true));
    v += __int_as_float(__builtin_amdgcn_update_dpp(0, __float_as_int(v), 0x143, 0xF, 0xF, true));
    return __int_as_float(__builtin_amdgcn_readlane(__float_as_int(v), 63));
}

// gfx950 VALU cross-lane exchange; a and b MUST be distinct SSA values.
template<int HALF>
__device__ __forceinline__ void swap_pl(float& a, float& b) {
    if constexpr (HALF == 32)
        asm("v_permlane32_swap_b32 %0, %1" : "+v"(a), "+v"(b));
    else
        asm("v_permlane16_swap_b32 %0, %1" : "+v"(a), "+v"(b));
}

// ---------- explicit VOP3P packed-f32 helpers ----------
__device__ __forceinline__ v2f pks_mul(v2f c, v2f a) {
    v2f d; asm("v_pk_mul_f32 %0, %1, %2" : "=v"(d) : "s"(c), "v"(a)); return d;
}
__device__ __forceinline__ v2f pks_fma(v2f c, v2f a, v2f b) {
    v2f d; asm("v_pk_fma_f32 %0, %1, %2, %3" : "=v"(d) : "s"(c), "v"(a), "v"(b)); return d;
}
// v-coefficient with LOW-half broadcast (coefficient pair's .y never read -> no splat mov)
__device__ __forceinline__ v2f pkv_mul_c(v2f c, v2f a) {
    v2f d; asm("v_pk_mul_f32 %0, %1, %2 op_sel:[0,0] op_sel_hi:[0,1]"
               : "=v"(d) : "v"(c), "v"(a)); return d;
}
__device__ __forceinline__ v2f pkv_fma_c(v2f c, v2f a, v2f b) {
    v2f d; asm("v_pk_fma_f32 %0, %1, %2, %3 op_sel:[0,0,0] op_sel_hi:[0,1,1]"
               : "=v"(d) : "v"(c), "v"(a), "v"(b)); return d;
}
// q3 variants: src1 broadcast from its LOW or HIGH 32-bit half via op_sel
__device__ __forceinline__ v2f pks_mul_blo(v2f c, v2f a) {
    v2f d; asm("v_pk_mul_f32 %0, %1, %2 op_sel:[0,0] op_sel_hi:[1,0]"
               : "=v"(d) : "s"(c), "v"(a)); return d;
}
__device__ __forceinline__ v2f pks_fma_blo(v2f c, v2f a, v2f b) {
    v2f d; asm("v_pk_fma_f32 %0, %1, %2, %3 op_sel:[0,0,0] op_sel_hi:[1,0,1]"
               : "=v"(d) : "s"(c), "v"(a), "v"(b)); return d;
}
__device__ __forceinline__ v2f pks_fma_bhi(v2f c, v2f a, v2f b) {
    v2f d; asm("v_pk_fma_f32 %0, %1, %2, %3 op_sel:[0,1,0] op_sel_hi:[1,1,1]"
               : "=v"(d) : "s"(c), "v"(a), "v"(b)); return d;
}

// ---- state: v2f AR[8], AI[8]; element e = 2k+h; qubit w(0..3) <-> e-bit(3-w);
// ---- qubits 4..9 <-> lane bits 5..0.
__device__ __forceinline__ float getv(const v2f (&A)[8], int e) {
    return (e & 1) ? A[e >> 1].y : A[e >> 1].x;
}
__device__ __forceinline__ void setv(v2f (&A)[8], int e, float v) {
    if (e & 1) A[e >> 1].y = v; else A[e >> 1].x = v;
}

template<int KM>
__device__ __forceinline__ void reg_gate_asm(const float* __restrict__ g,
                                             v2f (&AR)[8], v2f (&AI)[8]) {
    const v2f* __restrict__ gp = (const v2f*)g;
    const v2f c00r = gp[6],  c00i = gp[7],  c00in = gp[8];
    const v2f c01r = gp[9],  c01i = gp[10], c01in = gp[11];
    const v2f c10r = gp[12], c10i = gp[13], c10in = gp[14];
    const v2f c11r = gp[15], c11i = gp[16], c11in = gp[17];
#pragma unroll
    for (int k0 = 0; k0 < 8; ++k0) {
        if (k0 & KM) continue;
        const int k1 = k0 | KM;
        v2f A0 = AR[k0], I0 = AI[k0], A1 = AR[k1], I1 = AI[k1];
        v2f t = pks_mul(c00r, A0); t = pks_fma(c00in, I0, t);
        t = pks_fma(c01r, A1, t);  AR[k0] = pks_fma(c01in, I1, t);
        v2f u = pks_mul(c00r, I0); u = pks_fma(c00i, A0, u);
        u = pks_fma(c01r, I1, u);  AI[k0] = pks_fma(c01i, A1, u);
        v2f t2 = pks_mul(c10r, A0); t2 = pks_fma(c10in, I0, t2);
        t2 = pks_fma(c11r, A1, t2); AR[k1] = pks_fma(c11in, I1, t2);
        v2f u2 = pks_mul(c10r, I0); u2 = pks_fma(c10i, A0, u2);
        u2 = pks_fma(c11r, I1, u2); AI[k1] = pks_fma(c11i, A1, u2);
    }
}

__device__ __forceinline__ void reg_gate_q3_asm(const float* __restrict__ g,
                                                v2f (&AR)[8], v2f (&AI)[8]) {
    const v2f* __restrict__ gp = (const v2f*)g;
    const v2f P0 = gp[18], P1 = gp[19], P1n = gp[20];
    const v2f P2 = gp[21], P3 = gp[22], P3n = gp[23];
#pragma unroll
    for (int k = 0; k < 8; ++k) {
        v2f t = pks_mul_blo(P0, AR[k]);
        t = pks_fma_blo(P1n, AI[k], t);
        t = pks_fma_bhi(P2, AR[k], t);
        v2f nR = pks_fma_bhi(P3n, AI[k], t);
        v2f u = pks_mul_blo(P0, AI[k]);
        u = pks_fma_blo(P1, AR[k], u);
        u = pks_fma_bhi(P2, AI[k], u);
        v2f nI = pks_fma_bhi(P3, AR[k], u);
        AR[k] = nR; AI[k] = nI;
    }
}

template<int LB>
__device__ __forceinline__ void lane_gate_asm(const float* __restrict__ g, int lane,
                                              v2f (&AR)[8], v2f (&AI)[8]) {
    const bool side = (lane >> LB) & 1;
    v2f Cmr, Cmi, Cmin, Cpr, Cpi, Cpin;
    Cmr.x  = side ? g[6]  : g[0];
    Cmi.x  = side ? g[7]  : g[1];
    Cmin.x = side ? g[11] : g[8];
    Cpr.x  = side ? g[4]  : g[2];
    Cpi.x  = side ? g[5]  : g[3];
    Cpin.x = side ? g[10] : g[9];
#pragma unroll
    for (int k = 0; k < 8; ++k) {
        v2f PR, PI;
        PR.x = lxor<(1 << LB)>(AR[k].x); PR.y = lxor<(1 << LB)>(AR[k].y);
        PI.x = lxor<(1 << LB)>(AI[k].x); PI.y = lxor<(1 << LB)>(AI[k].y);
        v2f t = pkv_mul_c(Cmr, AR[k]); t = pkv_fma_c(Cmin, AI[k], t);
        t = pkv_fma_c(Cpr, PR, t);     v2f NR = pkv_fma_c(Cpin, PI, t);
        v2f u = pkv_mul_c(Cmr, AI[k]); u = pkv_fma_c(Cmi, AR[k], u);
        u = pkv_fma_c(Cpr, PI, u);     v2f NI = pkv_fma_c(Cpi, PR, u);
        AR[k] = NR; AI[k] = NI;
    }
}

template<int HALF>
__device__ __forceinline__ void lane_gate_pl_asm(const float* __restrict__ g,
                                                 v2f (&AR)[8], v2f (&AI)[8]) {
    const v2f* __restrict__ gp = (const v2f*)g;
    const v2f c00r = gp[6],  c00i = gp[7],  c00in = gp[8];
    const v2f c01r = gp[9],  c01i = gp[10], c01in = gp[11];
    const v2f c10r = gp[12], c10i = gp[13], c10in = gp[14];
    const v2f c11r = gp[15], c11i = gp[16], c11in = gp[17];
#pragma unroll
    for (int k0 = 0; k0 < 8; k0 += 2) {
        const int k1 = k0 + 1;
        float Xr0 = AR[k0].x, Xr1 = AR[k0].y, Yr0 = AR[k1].x, Yr1 = AR[k1].y;
        float Xi0 = AI[k0].x, Xi1 = AI[k0].y, Yi0 = AI[k1].x, Yi1 = AI[k1].y;
        swap_pl<HALF>(Xr0, Yr0); swap_pl<HALF>(Xr1, Yr1);
        swap_pl<HALF>(Xi0, Yi0); swap_pl<HALF>(Xi1, Yi1);
        v2f Xr; Xr.x = Xr0; Xr.y = Xr1;  v2f Yr; Yr.x = Yr0; Yr.y = Yr1;
        v2f Xi; Xi.x = Xi0; Xi.y = Xi1;  v2f Yi; Yi.x = Yi0; Yi.y = Yi1;
        v2f t = pks_mul(c00r, Xr); t = pks_fma(c00in, Xi, t);
        t = pks_fma(c01r, Yr, t);  v2f Pr = pks_fma(c01in, Yi, t);
        v2f u = pks_mul(c00r, Xi); u = pks_fma(c00i, Xr, u);
        u = pks_fma(c01r, Yi, u);  v2f Pi = pks_fma(c01i, Yr, u);
        v2f t2 = pks_mul(c10r, Xr); t2 = pks_fma(c10in, Xi, t2);
        t2 = pks_fma(c11r, Yr, t2); v2f Qr = pks_fma(c11in, Yi, t2);
        v2f u2 = pks_mul(c10r, Xi); u2 = pks_fma(c10i, Xr, u2);
        u2 = pks_fma(c11r, Yi, u2); v2f Qi = pks_fma(c11i, Yr, u2);
        float pr0 = Pr.x, pr1 = Pr.y, qr0 = Qr.x, qr1 = Qr.y;
        float pi0 = Pi.x, pi1 = Pi.y, qi0 = Qi.x, qi1 = Qi.y;
        swap_pl<HALF>(pr0, qr0); swap_pl<HALF>(pr1, qr1);
        swap_pl<HALF>(pi0, qi0); swap_pl<HALF>(pi1, qi1);
        AR[k0].x = pr0; AR[k0].y = pr1; AR[k1].x = qr0; AR[k1].y = qr1;
        AI[k0].x = pi0; AI[k0].y = pi1; AI[k1].x = qi0; AI[k1].y = qi1;
    }
}

// ---- compile-time CNOT-ring tables (element index e, 4 bits) ----
constexpr int rr_src(int rs, int e) {
    int s = e;
    for (int i = 3 - rs; i >= 0; --i) s ^= ((s >> (3 - i)) & 1) << (3 - i - rs);
    return s;
}
constexpr int rl_mask(int rs, int e) {
    int m = 0;
    for (int i = (4 - rs < 0 ? 0 : 4 - rs); i <= 3; ++i)
        if ((e >> (3 - i)) & 1) m |= 1 << (9 - i - rs);
    return m;
}

// gate sweep for layer L (10 Rot gates)
template<int L>
__device__ __forceinline__ void do_gates(const float* __restrict__ gt, int lane,
                                         v2f (&AR)[8], v2f (&AI)[8]) {
    const float* __restrict__ gb = gt + L * NQ * GSTRIDE;
    reg_gate_asm<4>(gb + 0 * GSTRIDE, AR, AI);   // qubit0: e-mask 8
    reg_gate_asm<2>(gb + 1 * GSTRIDE, AR, AI);   // qubit1: e-mask 4
    reg_gate_asm<1>(gb + 2 * GSTRIDE, AR, AI);   // qubit2: e-mask 2
    reg_gate_q3_asm(gb + 3 * GSTRIDE, AR, AI);   // qubit3: e-mask 1
    lane_gate_pl_asm<32>(gb + 4 * GSTRIDE, AR, AI);
    lane_gate_pl_asm<16>(gb + 5 * GSTRIDE, AR, AI);
    lane_gate_asm<3>(gb + 6 * GSTRIDE, lane, AR, AI);
    lane_gate_asm<2>(gb + 7 * GSTRIDE, lane, AR, AI);
    lane_gate_asm<1>(gb + 8 * GSTRIDE, lane, AR, AI);
    lane_gate_asm<0>(gb + 9 * GSTRIDE, lane, AR, AI);
}

// CNOT-ring movement for layer L: RR+RL+LL folded into one bpermute gather, then LR
template<int L>
__device__ __forceinline__ void do_move(int lane, v2f (&AR)[8], v2f (&AI)[8]) {
    constexpr int rs = L + 1;
    int y = lane;
#pragma unroll
    for (int i = 9 - rs; i >= 4; --i)
        y ^= ((y >> (9 - i)) & 1) << (9 - i - rs);
    const int base = y << 2;
    {
        float nr[16], ni[16];
#pragma unroll
        for (int e = 0; e < 16; ++e) {
            const int src = rr_src(rs, e);
            const int am  = rl_mask(rs, e) << 2;
            nr[e] = __int_as_float(__builtin_amdgcn_ds_bpermute(base ^ am, __float_as_int(getv(AR, src))));
            ni[e] = __int_as_float(__builtin_amdgcn_ds_bpermute(base ^ am, __float_as_int(getv(AI, src))));
        }
#pragma unroll
        for (int k = 0; k < 8; ++k) {
            AR[k].x = nr[2 * k]; AR[k].y = nr[2 * k + 1];
            AI[k].x = ni[2 * k]; AI[k].y = ni[2 * k + 1];
        }
    }
    // LR: predicated element-pair swaps
#pragma unroll
    for (int i = 10 - rs; i <= 9; ++i) {
        const bool p = (lane >> (9 - i)) & 1;
        const int tm = 1 << (13 - i - rs);
#pragma unroll
        for (int e = 0; e < 16; ++e) {
            if (!(e & tm)) {
                const int e1 = e | tm;
                float v0r = getv(AR, e), v1r = getv(AR, e1);
                setv(AR, e, p ? v1r : v0r); setv(AR, e1, p ? v0r : v1r);
                float v0i = getv(AI, e), v1i = getv(AI, e1);
                setv(AI, e, p ? v1i : v0i); setv(AI, e1, p ? v0i : v1i);
            }
        }
    }
}

__device__ __forceinline__ float ftanh(float s) {
    float e = __expf(2.f * s);
    return 1.f - 2.f / (e + 1.f);
}

// ---------------- prep: gate table (48 floats/gate) + W1 pair-packed repack ----------------
// w1q[k2][lane] = {W1[2l][2k2], W1[2l+1][2k2], W1[2l][2k2+1], W1[2l+1][2k2+1]}
// -> fused MLP loads one float4 per 2 k-steps (32 loads instead of 64).
__global__ void prep_kernel(const float* __restrict__ qw, const float* __restrict__ W1,
                            float* __restrict__ gtab, float* __restrict__ w1q) {
    int tid = blockIdx.x * 256 + threadIdx.x;
    if (tid < 128 * 64) {
        int k2 = tid >> 6, l = tid & 63;
        float4 q;
        q.x = W1[(size_t)(2 * l)     * INFEAT + 2 * k2];
        q.y = W1[(size_t)(2 * l + 1) * INFEAT + 2 * k2];
        q.z = W1[(size_t)(2 * l)     * INFEAT + 2 * k2 + 1];
        q.w = W1[(size_t)(2 * l + 1) * INFEAT + 2 * k2 + 1];
        ((float4*)w1q)[tid] = q;
    }
    if (blockIdx.x == 0 && threadIdx.x < NL * NQ) {
        int t = threadIdx.x;
        float phi = qw[t * 3 + 0], th = qw[t * 3 + 1], om = qw[t * 3 + 2];
        float c = __cosf(th * 0.5f), s = __sinf(th * 0.5f);
        float a = 0.5f * (phi + om), b = 0.5f * (phi - om);
        float ca = __cosf(a), sa = __sinf(a);
        float cb = __cosf(b), sb = __sinf(b);
        float m00r = ca * c,  m00i = -sa * c;
        float m01r = -cb * s, m01i = -sb * s;
        float m10r = cb * s,  m10i = -sb * s;
        float m11r = ca * c,  m11i = sa * c;
        float* g = gtab + t * GSTRIDE;
        g[0] = m00r; g[1] = m00i; g[2] = m01r; g[3] = m01i;
        g[4] = m10r; g[5] = m10i; g[6] = m11r; g[7] = m11i;
        g[8] = -m00i; g[9] = -m01i; g[10] = -m10i; g[11] = -m11i;
        g[12] = g[13] = m00r;  g[14] = g[15] = m00i;  g[16] = g[17] = -m00i;
        g[18] = g[19] = m01r;  g[20] = g[21] = m01i;  g[22] = g[23] = -m01i;
        g[24] = g[25] = m10r;  g[26] = g[27] = m10i;  g[28] = g[29] = -m10i;
        g[30] = g[31] = m11r;  g[32] = g[33] = m11i;  g[34] = g[35] = -m11i;
        g[36] = m00r;  g[37] = m10r;
        g[38] = m00i;  g[39] = m10i;
        g[40] = -m00i; g[41] = -m10i;
        g[42] = m01r;  g[43] = m11r;
        g[44] = m01i;  g[45] = m11i;
        g[46] = -m01i; g[47] = -m11i;
    }
}

// ---------------- fused kernel: K-split MLP -> circuit -> head ----------------
// (256,4) caps VGPR at 64 = the occupancy cliff (r13: occ 31->40%).
// TRIPWIRE: WRITE_SIZE >> 1 MB means spills returned.
__global__ __launch_bounds__(256, 4) void fused_kernel(
    const float* __restrict__ x, const float* __restrict__ w1q,
    const float* __restrict__ b1, const float* __restrict__ W2,
    const float* __restrict__ b2, const float* __restrict__ gtab,
    const float* __restrict__ W3, const float* __restrict__ b3,
    const float* __restrict__ W4, const float* __restrict__ b4,
    float* __restrict__ out)
{
    __shared__ float w3s[HID * 11];
    __shared__ float b3s[HID], w4s[HID];
    __shared__ float b4s;
    __shared__ v2f hpart[4][4][64];   // [k-slice wave][row][lane(2 cols)]

    const int t = threadIdx.x;
    for (int f = t; f < HID * NQ; f += 256) {
        int c = f / NQ, k = f - c * NQ;
        w3s[c * 11 + k] = W3[f];
    }
    if (t < HID) { b3s[t] = b3[t]; w4s[t] = W4[t]; }
    if (t == 0) b4s = b4[0];

    const int lane = t & 63;
    const int wid = t >> 6;
    const int row0 = blockIdx.x * 4;
    const int ukw = __builtin_amdgcn_readfirstlane(wid);

    // ---- MLP phase 1: partial h for all 4 rows over k-slice [64*ukw, 64*ukw+64) ----
    v2f acc[4];
#pragma unroll
    for (int r = 0; r < 4; ++r) acc[r] = (v2f)(0.f);
    const float4* __restrict__ xr0 = (const float4*)(x + (size_t)(row0 + 0) * INFEAT + ukw * 64);
    const float4* __restrict__ xr1 = (const float4*)(x + (size_t)(row0 + 1) * INFEAT + ukw * 64);
    const float4* __restrict__ xr2 = (const float4*)(x + (size_t)(row0 + 2) * INFEAT + ukw * 64);
    const float4* __restrict__ xr3 = (const float4*)(x + (size_t)(row0 + 3) * INFEAT + ukw * 64);
    // k2 base for this slice: ukw*32 (64 k's = 32 pairs)
    const float4* __restrict__ w1p = (const float4*)w1q + (size_t)ukw * 32 * 64 + lane;
#pragma unroll 4
    for (int kk4 = 0; kk4 < 16; ++kk4) {
        float4 x0 = xr0[kk4], x1 = xr1[kk4], x2 = xr2[kk4], x3 = xr3[kk4];
        float xk[4][4] = {{x0.x, x0.y, x0.z, x0.w}, {x1.x, x1.y, x1.z, x1.w},
                          {x2.x, x2.y, x2.z, x2.w}, {x3.x, x3.y, x3.z, x3.w}};
        float4 q0 = w1p[(2 * kk4 + 0) * 64];
        float4 q1 = w1p[(2 * kk4 + 1) * 64];
        v2f w0; w0.x = q0.x; w0.y = q0.y;   // k = 4kk4
        v2f w1; w1.x = q0.z; w1.y = q0.w;   // k = 4kk4+1
        v2f w2; w2.x = q1.x; w2.y = q1.y;   // k = 4kk4+2
        v2f w3; w3.x = q1.z; w3.y = q1.w;   // k = 4kk4+3
#pragma unroll
        for (int r = 0; r < 4; ++r) {
            v2f xb;
            xb.x = xk[r][0]; xb.y = xk[r][0];
            acc[r] = __builtin_elementwise_fma(xb, w0, acc[r]);
            xb.x = xk[r][1]; xb.y = xk[r][1];
            acc[r] = __builtin_elementwise_fma(xb, w1, acc[r]);
            xb.x = xk[r][2]; xb.y = xk[r][2];
            acc[r] = __builtin_elementwise_fma(xb, w2, acc[r]);
            xb.x = xk[r][3]; xb.y = xk[r][3];
            acc[r] = __builtin_elementwise_fma(xb, w3, acc[r]);
        }
    }
#pragma unroll
    for (int r = 0; r < 4; ++r) hpart[wid][r][lane] = acc[r];
    __syncthreads();

    // ---- MLP phase 2 ----
    v2f hs = hpart[0][wid][lane];
    hs += hpart[1][wid][lane];
    hs += hpart[2][wid][lane];
    hs += hpart[3][wid][lane];
    float2 b1v = ((const float2*)b1)[lane];
    float h0 = fmaxf(hs.x + b1v.x, 0.f);
    float h1 = fmaxf(hs.y + b1v.y, 0.f);

    const int row = row0 + wid;

    // ---- angles = tanh(h@W2^T + b2), DPP-chain reductions (0 DS) ----
    float cth[NQ], sth[NQ];
#pragma unroll
    for (int w = 0; w < NQ; ++w) {
        float2 w2v = ((const float2*)(W2 + (size_t)w * HID))[lane];
        float aw = dpp_sum(fmaf(h0, w2v.x, h1 * w2v.y)) + b2[w];
        float th = ftanh(aw) * 0.5f;
        cth[w] = __cosf(th); sth[w] = __sinf(th);
    }

    // ---- fused RY + layer-0 Rot product state (low-pressure construction) ----
    float Lr, Li;
    {
        const float* __restrict__ g = gtab + 4 * GSTRIDE;
        bool bw = (lane >> 5) & 1;
        float g0 = bw ? g[4] : g[0], g1 = bw ? g[5] : g[1];
        float g2 = bw ? g[6] : g[2], g3 = bw ? g[7] : g[3];
        Lr = fmaf(g0, cth[4], g2 * sth[4]);
        Li = fmaf(g1, cth[4], g3 * sth[4]);
    }
#pragma unroll
    for (int w = 5; w < 10; ++w) {
        const float* __restrict__ g = gtab + w * GSTRIDE;
        bool bw = (lane >> (9 - w)) & 1;
        float g0 = bw ? g[4] : g[0], g1 = bw ? g[5] : g[1];
        float g2 = bw ? g[6] : g[2], g3 = bw ? g[7] : g[3];
        float fr = fmaf(g0, cth[w], g2 * sth[w]);
        float fi = fmaf(g1, cth[w], g3 * sth[w]);
        float nr = Lr * fr - Li * fi;
        float ni = Lr * fi + Li * fr;
        Lr = nr; Li = ni;
    }
    float q01r[4], q01i[4], q23r[4], q23i[4];
    {
        const float* __restrict__ ga = gtab + 0 * GSTRIDE;
        const float* __restrict__ gb = gtab + 1 * GSTRIDE;
        float a0r = fmaf(ga[0], cth[0], ga[2] * sth[0]);
        float a0i = fmaf(ga[1], cth[0], ga[3] * sth[0]);
        float b0r = fmaf(ga[4], cth[0], ga[6] * sth[0]);
        float b0i = fmaf(ga[5], cth[0], ga[7] * sth[0]);
        float a1r = fmaf(gb[0], cth[1], gb[2] * sth[1]);
        float a1i = fmaf(gb[1], cth[1], gb[3] * sth[1]);
        float b1r = fmaf(gb[4], cth[1], gb[6] * sth[1]);
        float b1i = fmaf(gb[5], cth[1], gb[7] * sth[1]);
#pragma unroll
        for (int j = 0; j < 4; ++j) {
            float f0r = (j & 2) ? b0r : a0r, f0i = (j & 2) ? b0i : a0i;
            float f1r = (j & 1) ? b1r : a1r, f1i = (j & 1) ? b1i : a1i;
            q01r[j] = f0r * f1r - f0i * f1i;
            q01i[j] = f0r * f1i + f0i * f1r;
        }
    }
    {
        const float* __restrict__ ga = gtab + 2 * GSTRIDE;
        const float* __restrict__ gb = gtab + 3 * GSTRIDE;
        float a2r = fmaf(ga[0], cth[2], ga[2] * sth[2]);
        float a2i = fmaf(ga[1], cth[2], ga[3] * sth[2]);
        float b2r = fmaf(ga[4], cth[2], ga[6] * sth[2]);
        float b2i = fmaf(ga[5], cth[2], ga[7] * sth[2]);
        float a3r = fmaf(gb[0], cth[3], gb[2] * sth[3]);
        float a3i = fmaf(gb[1], cth[3], gb[3] * sth[3]);
        float b3r = fmaf(gb[4], cth[3], gb[6] * sth[3]);
        float b3i = fmaf(gb[5], cth[3], gb[7] * sth[3]);
#pragma unroll
        for (int j = 0; j < 4; ++j) {
            float f2r = (j & 2) ? b2r : a2r, f2i = (j & 2) ? b2i : a2i;
            float f3r = (j & 1) ? b3r : a3r, f3i = (j & 1) ? b3i : a3i;
            q23r[j] = f2r * f3r - f2i * f3i;
            q23i[j] = f2r * f3i + f2i * f3r;
        }
    }
    v2f AR[8], AI[8];
#pragma unroll
    for (int e = 0; e < 16; ++e) {
        const int jh = e >> 2, jl = e & 3;
        float tr = q01r[jh] * q23r[jl] - q01i[jh] * q23i[jl];
        float ti = q01r[jh] * q23i[jl] + q01i[jh] * q23r[jl];
        float ar = tr * Lr - ti * Li;
        float ai = tr * Li + ti * Lr;
        setv(AR, e, ar); setv(AI, e, ai);
    }

    // ---- layer-0 movement, then layers 1..3 (gates + movement) ----
    do_move<0>(lane, AR, AI);
    do_gates<1>(gtab, lane, AR, AI);
    do_move<1>(lane, AR, AI);
    do_gates<2>(gtab, lane, AR, AI);
    do_move<2>(lane, AR, AI);
    do_gates<3>(gtab, lane, AR, AI);
    do_move<3>(lane, AR, AI);

    // ---- Z expectations ----
    v2f Pk[8];
#pragma unroll
    for (int k = 0; k < 8; ++k) Pk[k] = AR[k] * AR[k] + AI[k] * AI[k];
    v2f S = Pk[0] + Pk[1] + Pk[2] + Pk[3] + Pk[4] + Pk[5] + Pk[6] + Pk[7];
    float ptot = S.x + S.y;
    v2f Sq0 = Pk[4] + Pk[5] + Pk[6] + Pk[7];
    v2f Sq1 = Pk[2] + Pk[3] + Pk[6] + Pk[7];
    v2f Sq2 = Pk[1] + Pk[3] + Pk[5] + Pk[7];
    float es0 = dpp_sum(ptot - 2.f * (Sq0.x + Sq0.y));
    float es1 = dpp_sum(ptot - 2.f * (Sq1.x + Sq1.y));
    float es2 = dpp_sum(ptot - 2.f * (Sq2.x + Sq2.y));
    float es3 = dpp_sum(ptot - 2.f * S.y);
    // lane-qubit expectations via one Walsh-Hadamard butterfly on ptot (needs true xor)
    float Wv = ptot;
    {
        float p;
        p = lxor<1>(Wv);  Wv = (lane & 1)  ? p - Wv : Wv + p;
        p = lxor<2>(Wv);  Wv = (lane & 2)  ? p - Wv : Wv + p;
        p = lxor<4>(Wv);  Wv = (lane & 4)  ? p - Wv : Wv + p;
        p = lxor<8>(Wv);  Wv = (lane & 8)  ? p - Wv : Wv + p;
        p = lxor<16>(Wv); Wv = (lane & 16) ? p - Wv : Wv + p;
        p = lxor<32>(Wv); Wv = (lane & 32) ? p - Wv : Wv + p;
    }
    const int wvi = __float_as_int(Wv);
    float es[NQ];
    es[0] = es0; es[1] = es1; es[2] = es2; es[3] = es3;
    es[4] = __int_as_float(__builtin_amdgcn_readlane(wvi, 32));
    es[5] = __int_as_float(__builtin_amdgcn_readlane(wvi, 16));
    es[6] = __int_as_float(__builtin_amdgcn_readlane(wvi, 8));
    es[7] = __int_as_float(__builtin_amdgcn_readlane(wvi, 4));
    es[8] = __int_as_float(__builtin_amdgcn_readlane(wvi, 2));
    es[9] = __int_as_float(__builtin_amdgcn_readlane(wvi, 1));

    // ---- head ----
    float accv = 0.f;
#pragma unroll
    for (int j = 0; j < 2; ++j) {
        int c = lane + 64 * j;
        float d = b3s[c];
#pragma unroll
        for (int k = 0; k < NQ; ++k) d = fmaf(w3s[c * 11 + k], es[k], d);
        d = fmaxf(d, 0.f);
        accv = fmaf(d, w4s[c], accv);
    }
    accv = dpp_sum(accv);
    if (lane == 0) out[row] = accv + b4s;
}

extern "C" void kernel_launch(void* const* d_in, const int* in_sizes, int n_in,
                              void* d_out, int out_size, void* d_ws, size_t ws_size,
                              hipStream_t stream) {
    const float* x  = (const float*)d_in[0];
    const float* W1 = (const float*)d_in[1];
    const float* b1 = (const float*)d_in[2];
    const float* W2 = (const float*)d_in[3];
    const float* b2 = (const float*)d_in[4];
    const float* qw = (const float*)d_in[5];
    const float* W3 = (const float*)d_in[6];
    const float* b3 = (const float*)d_in[7];
    const float* W4 = (const float*)d_in[8];
    const float* b4 = (const float*)d_in[9];
    float* gtab = (float*)d_ws;                 // 40*48 = 1920 floats
    float* w1q  = (float*)d_ws + 2048;          // 32768 floats (pair-packed)
    float* out  = (float*)d_out;

    prep_kernel<<<(128 * 64 + 255) / 256, 256, 0, stream>>>(qw, W1, gtab, w1q);
    fused_kernel<<<BATCH / 4, 256, 0, stream>>>(x, w1q, b1, W2, b2, gtab, W3, b3, W4, b4, out);
}